// Round 9
// baseline (1604.544 us; speedup 1.0000x reference)
//
#include <hip/hip_runtime.h>
#include <hip/hip_bf16.h>

#define THREADS 256
typedef __hip_bfloat16 bf16;

typedef __bf16 v8bf __attribute__((ext_vector_type(8)));
typedef float  v4f  __attribute__((ext_vector_type(4)));

__device__ __forceinline__ float bfl(unsigned u){ return __uint_as_float(u << 16); }
__device__ __forceinline__ float bfh(unsigned u){ return __uint_as_float(u & 0xffff0000u); }

// ---------------- CSR build (group edges by destination) ----------------
__global__ void hist_k(const int* __restrict__ ei, int* __restrict__ cnt, int E, int ET){
  int i = blockIdx.x*THREADS + threadIdx.x;
  if (i >= ET) return;
  int d = (i < E) ? ei[E + i] : (i - E);   // self-loops appended
  atomicAdd(&cnt[d], 1);
}

__global__ void scan1_k(const int* __restrict__ deg, int* __restrict__ off,
                        int* __restrict__ bsum, int n){
  __shared__ int sh[1024];
  int i = blockIdx.x*1024 + threadIdx.x;
  int v = (i < n) ? deg[i] : 0;
  sh[threadIdx.x] = v;
  __syncthreads();
  for (int s = 1; s < 1024; s <<= 1){
    int t = (threadIdx.x >= s) ? sh[threadIdx.x - s] : 0;
    __syncthreads();
    sh[threadIdx.x] += t;
    __syncthreads();
  }
  if (i < n) off[i+1] = sh[threadIdx.x];
  if (threadIdx.x == 1023) bsum[blockIdx.x] = sh[1023];
}

__global__ void scan2_k(int* __restrict__ bsum, int nb){
  __shared__ int sh[256];
  int v = (threadIdx.x < nb) ? bsum[threadIdx.x] : 0;
  sh[threadIdx.x] = v;
  __syncthreads();
  for (int s = 1; s < 256; s <<= 1){
    int t = (threadIdx.x >= s) ? sh[threadIdx.x - s] : 0;
    __syncthreads();
    sh[threadIdx.x] += t;
    __syncthreads();
  }
  if (threadIdx.x < nb) bsum[threadIdx.x] = sh[threadIdx.x] - v;  // exclusive
}

__global__ void scan3_k(int* __restrict__ off, const int* __restrict__ bsum, int n){
  int i = blockIdx.x*1024 + threadIdx.x;
  if (i < n) off[i+1] += bsum[blockIdx.x];
  if (i == 0) off[0] = 0;
}

__global__ void scatter_k(const int* __restrict__ ei, const int* __restrict__ off,
                          int* __restrict__ cur, int* __restrict__ csr,
                          int* __restrict__ csrd, int E, int ET){
  int i = blockIdx.x*THREADS + threadIdx.x;
  if (i >= ET) return;
  int s, d;
  if (i < E){ s = ei[i]; d = ei[E+i]; } else { s = i - E; d = i - E; }
  int p = off[d] + atomicAdd(&cur[d], 1);
  csr[p] = s;
  csrd[p] = d;
}

// ---------------- dtype prep ----------------
__global__ void convf2b_k(const float4* __restrict__ in, uint2* __restrict__ out, int n4){
  int i = blockIdx.x*THREADS + threadIdx.x;
  if (i >= n4) return;
  float4 v = in[i];
  union { bf16 h[4]; uint2 u; } cv;
  cv.h[0] = __float2bfloat16(v.x); cv.h[1] = __float2bfloat16(v.y);
  cv.h[2] = __float2bfloat16(v.z); cv.h[3] = __float2bfloat16(v.w);
  out[i] = cv.u;
}

// WT[c*K + k] = bf16(W[k*COUT + c])
__global__ void wt_k(const float* __restrict__ W, bf16* __restrict__ WT, int K, int COUT){
  int i = blockIdx.x*THREADS + threadIdx.x;
  if (i >= K*COUT) return;
  int k = i / COUT, c = i - k*COUT;
  WT[(size_t)c*K + k] = __float2bfloat16(W[i]);
}

// extra B-columns for fused alpha: WTX rows COUT..COUT+2 = W_h @ as_h, COUT+3..+5 = W_h @ ad_h
__global__ void va_k(const float* __restrict__ W, const float* __restrict__ as,
                     const float* __restrict__ ad, bf16* __restrict__ WTX,
                     int K, int C, int COUT){
  int i = blockIdx.x*THREADS + threadIdx.x;
  if (i >= 6*K) return;
  int k = i % K, c6 = i / K;
  int h = (c6 < 3) ? c6 : c6 - 3;
  const float* a = ((c6 < 3) ? as : ad) + h*C;
  const float* wp = W + (size_t)k*COUT + h*C;
  float s = 0.f;
  for (int cc = 0; cc < C; cc++) s += wp[cc]*a[cc];
  WTX[(size_t)(COUT + c6)*K + k] = __float2bfloat16(s);
}

// ---------------- MFMA GEMM fused with alpha: C = A@B, aS/aD from extra tile ----
template<int K, int COUT>
__global__ void __launch_bounds__(256) gemm_mfma_k(
    const bf16* __restrict__ A, const bf16* __restrict__ BT,
    bf16* __restrict__ C, float* __restrict__ aS4, float* __restrict__ aD4,
    int nRowTiles)
{
  int wave = threadIdx.x >> 6, lane = threadIdx.x & 63;
  int rt = blockIdx.x*4 + wave;
  if (rt >= nRowTiles) return;
  int half = lane & 15;
  int quad = lane >> 4;
  const __bf16* aBase = (const __bf16*)A + (size_t)(rt*16 + half)*K + quad*8;
  v8bf aF[K/32];
  #pragma unroll
  for (int kk = 0; kk < K/32; kk++) aF[kk] = *(const v8bf*)(aBase + kk*32);
  #pragma unroll
  for (int cb = 0; cb < COUT + 16; cb += 16){
    const __bf16* bBase = (const __bf16*)BT + (size_t)(cb + half)*K + quad*8;
    v4f acc = {0.f, 0.f, 0.f, 0.f};
    #pragma unroll
    for (int kk = 0; kk < K/32; kk++)
      acc = __builtin_amdgcn_mfma_f32_16x16x32_bf16(aF[kk], *(const v8bf*)(bBase + kk*32), acc, 0, 0, 0);
    int orow = rt*16 + quad*4;                 // D: col=lane&15, row=quad*4+reg
    if (cb < COUT){
      bf16* cp = C + (size_t)orow*COUT + cb + half;
      #pragma unroll
      for (int r = 0; r < 4; r++)
        cp[(size_t)r*COUT] = __float2bfloat16(acc[r]);
    } else if (half < 6){
      #pragma unroll
      for (int r = 0; r < 4; r++){
        int row = orow + r;
        if (half < 3) aS4[row*4 + half]     = acc[r];
        else          aD4[row*4 + half - 3] = acc[r];
      }
    }
  }
}

// ---------------- per-edge softmax numerators + per-node denominators ----------------
__global__ void wgt_k(const int* __restrict__ csr, const int* __restrict__ csrd,
                      const float* __restrict__ aS4, const float* __restrict__ aD4,
                      float* __restrict__ wbuf, float* __restrict__ den4, int ET)
{
  int i = blockIdx.x*THREADS + threadIdx.x;
  if (i >= ET) return;
  int s = csr[i], d = csrd[i];
  const float4 as = *(const float4*)(aS4 + 4*s);
  const float4 ad = *(const float4*)(aD4 + 4*d);
  float x0 = as.x + ad.x; x0 = (x0 > 0.f) ? x0 : 0.2f*x0;
  float x1 = as.y + ad.y; x1 = (x1 > 0.f) ? x1 : 0.2f*x1;
  float x2 = as.z + ad.z; x2 = (x2 > 0.f) ? x2 : 0.2f*x2;
  float w0 = __expf(x0), w1 = __expf(x1), w2 = __expf(x2);
  float4 w = {w0, w1, w2, 0.f};
  *(float4*)(wbuf + 4*i) = w;
  atomicAdd(den4 + 4*d + 0, w0);
  atomicAdd(den4 + 4*d + 1, w1);
  atomicAdd(den4 + 4*d + 2, w2);
}

// ---------------- weighted aggregation (GRP lanes per dst node) ----------------
// Denominator precomputed in den4; per-edge: csr dword + own-head w dword + 8B gather + 4 FMA.
template<int HC, int CSH, int GRP>
__global__ void __launch_bounds__(256) agg_k(
    const int* __restrict__ off, const int* __restrict__ csr,
    const bf16* __restrict__ hbuf, const float* __restrict__ wbuf,
    const float* __restrict__ den4, const float* __restrict__ bias,
    float* __restrict__ outF, bf16* __restrict__ outB,
    int n, int doElu)
{
  constexpr int NPW = 64 / GRP;
  int lane = threadIdx.x & 63;
  int wv = (blockIdx.x*256 + threadIdx.x) >> 6;
  int q = lane % GRP;
  int node = wv*NPW + lane/GRP;
  if (node >= n) return;
  const bool act = q < HC/4;
  if (!act) return;
  int e0 = off[node], e1 = off[node+1];
  const int hq = (4*q) >> CSH;               // head of this lane's 4 channels
  float inv = 1.f / (den4[4*node + hq] + 1e-16f);
  float a0 = 0.f, a1 = 0.f, a2 = 0.f, a3 = 0.f;
  const size_t hoff = 4*q;
  const float* wp = wbuf + hq;
  int e = e0;
  for (; e + 4 <= e1; e += 4){
    int s0 = csr[e+0], s1 = csr[e+1], s2 = csr[e+2], s3 = csr[e+3];
    float w0 = wp[4*(e+0)];
    float w1 = wp[4*(e+1)];
    float w2 = wp[4*(e+2)];
    float w3 = wp[4*(e+3)];
    uint2 u0 = *(const uint2*)(hbuf + (size_t)s0*HC + hoff);
    uint2 u1 = *(const uint2*)(hbuf + (size_t)s1*HC + hoff);
    uint2 u2 = *(const uint2*)(hbuf + (size_t)s2*HC + hoff);
    uint2 u3 = *(const uint2*)(hbuf + (size_t)s3*HC + hoff);
    a0 += w0*bfl(u0.x); a1 += w0*bfh(u0.x); a2 += w0*bfl(u0.y); a3 += w0*bfh(u0.y);
    a0 += w1*bfl(u1.x); a1 += w1*bfh(u1.x); a2 += w1*bfl(u1.y); a3 += w1*bfh(u1.y);
    a0 += w2*bfl(u2.x); a1 += w2*bfh(u2.x); a2 += w2*bfl(u2.y); a3 += w2*bfh(u2.y);
    a0 += w3*bfl(u3.x); a1 += w3*bfh(u3.x); a2 += w3*bfl(u3.y); a3 += w3*bfh(u3.y);
  }
  for (; e < e1; e++){
    int s = csr[e];
    float w = wp[4*e];
    uint2 u = *(const uint2*)(hbuf + (size_t)s*HC + hoff);
    a0 += w*bfl(u.x); a1 += w*bfh(u.x); a2 += w*bfl(u.y); a3 += w*bfh(u.y);
  }
  {
    const float4 b = *(const float4*)(bias + 4*q);
    float r0 = a0*inv + b.x, r1 = a1*inv + b.y, r2 = a2*inv + b.z, r3 = a3*inv + b.w;
    if (doElu){
      r0 = (r0 > 0.f) ? r0 : (__expf(r0) - 1.f);
      r1 = (r1 > 0.f) ? r1 : (__expf(r1) - 1.f);
      r2 = (r2 > 0.f) ? r2 : (__expf(r2) - 1.f);
      r3 = (r3 > 0.f) ? r3 : (__expf(r3) - 1.f);
    }
    if (outF){
      float4 o = {r0, r1, r2, r3};
      *(float4*)(outF + (size_t)node*HC + 4*q) = o;
    }
    if (outB){
      union { bf16 h[4]; uint2 u; } cv;
      cv.h[0] = __float2bfloat16(r0); cv.h[1] = __float2bfloat16(r1);
      cv.h[2] = __float2bfloat16(r2); cv.h[3] = __float2bfloat16(r3);
      *(uint2*)(outB + (size_t)node*HC + 4*q) = cv.u;
    }
  }
}

// ---------------- graph boundaries via binary search on sorted batch ----------------
__global__ void gboff_k(const int* __restrict__ batch, int* __restrict__ goff, int n, int G){
  int g = blockIdx.x*THREADS + threadIdx.x;
  if (g > G) return;
  if (g == G){ goff[G] = n; return; }
  int lo = 0, hi = n;
  while (lo < hi){ int mid = (lo + hi) >> 1; if (batch[mid] < g) lo = mid + 1; else hi = mid; }
  goff[g] = lo;
}

// ---------------- fused mean-pool + relu + linear + sigmoid + BCE (wave per graph) ---
__global__ void __launch_bounds__(256) pool_logits_k(
    const float* __restrict__ h3, const int* __restrict__ goff,
    const float* __restrict__ Wl, const float* __restrict__ bl,
    const float* __restrict__ y, float* __restrict__ outp,
    float* __restrict__ lossAcc, int G)
{
  int lane = threadIdx.x & 63;
  int g = (blockIdx.x*256 + threadIdx.x) >> 6;
  if (g >= G) return;
  int n0 = goff[g], n1 = goff[g+1];
  int cnt = n1 - n0;
  float acc = 0.f, acc2 = 0.f, wl = 0.f;
  if (lane < 48){
    wl = Wl[lane];
    const float* p = h3 + (size_t)n0*48 + lane;
    int i = 0;
    for (; i + 2 <= cnt; i += 2){ acc += p[(size_t)i*48]; acc2 += p[(size_t)(i+1)*48]; }
    if (i < cnt) acc += p[(size_t)i*48];
    acc += acc2;
  }
  float inv = 1.f / fmaxf((float)cnt, 1.f);
  float v = fmaxf(acc*inv, 0.f) * wl;
  for (int o = 32; o > 0; o >>= 1) v += __shfl_down(v, o);
  if (lane == 0){
    float logit = v + bl[0];
    outp[g] = 1.f / (1.f + __expf(-logit));
    float t = y[g];
    float sp = (logit > 0.f) ? (logit + log1pf(__expf(-logit))) : log1pf(__expf(logit));
    atomicAdd(lossAcc, sp - t*logit);
  }
}

__global__ void fin_k(const float* __restrict__ lossAcc, float* __restrict__ outp, int gtot){
  outp[gtot] = lossAcc[0] / (float)gtot;
}

// ---------------- launch ----------------
extern "C" void kernel_launch(void* const* d_in, const int* in_sizes, int n_in,
                              void* d_out, int out_size, void* d_ws, size_t ws_size,
                              hipStream_t stream)
{
  (void)n_in; (void)out_size; (void)ws_size;
  const float* x    = (const float*)d_in[0];
  const float* y    = (const float*)d_in[1];
  const int*  ei    = (const int*)d_in[2];
  const int*  batch = (const int*)d_in[3];
  const float* W1 = (const float*)d_in[4];
  const float* as1= (const float*)d_in[5];
  const float* ad1= (const float*)d_in[6];
  const float* b1 = (const float*)d_in[7];
  const float* W2 = (const float*)d_in[8];
  const float* as2= (const float*)d_in[9];
  const float* ad2= (const float*)d_in[10];
  const float* b2 = (const float*)d_in[11];
  const float* W3 = (const float*)d_in[12];
  const float* as3= (const float*)d_in[13];
  const float* ad3= (const float*)d_in[14];
  const float* b3 = (const float*)d_in[15];
  const float* Wl = (const float*)d_in[16];
  const float* bl = (const float*)d_in[17];
  float* outp = (float*)d_out;

  int Nn = in_sizes[0] / 128;   // 100000 (multiple of 16)
  int Gg = in_sizes[1];
  int Ee = in_sizes[2] / 2;
  int ET = Ee + Nn;

  char* p = (char*)d_ws;
  auto carve = [&](size_t bytes) -> void* {
    void* r = (void*)p; p += (bytes + 255) & ~(size_t)255; return r;
  };
  int*   off     = (int*)  carve((size_t)(Nn+1)*4);
  int*   cnt     = (int*)  carve((size_t)Nn*4);
  int*   csr     = (int*)  carve((size_t)ET*4);
  int*   csrd    = (int*)  carve((size_t)ET*4);
  float* wbuf    = (float*)carve((size_t)ET*4*4);
  int*   bsum    = (int*)  carve(256*4);
  float* aS4     = (float*)carve((size_t)Nn*4*4);
  float* aD4     = (float*)carve((size_t)Nn*4*4);
  float* den4    = (float*)carve((size_t)Nn*4*4);
  int*   goff    = (int*)  carve((size_t)(Gg+1)*4);
  float* lossAcc = (float*)carve(4);
  bf16*  WT1     = (bf16*) carve((size_t)(192+16)*128*2);
  bf16*  WT2     = (bf16*) carve((size_t)(96+16)*192*2);
  bf16*  WT3     = (bf16*) carve((size_t)(48+16)*96*2);
  bf16*  bufH    = (bf16*) carve((size_t)Nn*192*2);   // GEMM out (h), agg in
  bf16*  bufA    = (bf16*) carve((size_t)Nn*192*2);   // GEMM A-operand
  // layer-3 f32 out for pooling: alias into the unused tail of bufH's region
  float* bufO    = (float*)((char*)bufH + ((size_t)Nn*96 + 255 & ~(size_t)255));

  int NB = (Nn + 1023) / 1024;
  int ebk = (ET + THREADS - 1) / THREADS;

  // CSR by destination
  hipMemsetAsync(cnt, 0, (size_t)Nn*4, stream);
  hist_k<<<ebk, THREADS, 0, stream>>>(ei, cnt, Ee, ET);
  scan1_k<<<NB, 1024, 0, stream>>>(cnt, off, bsum, Nn);
  scan2_k<<<1, 256, 0, stream>>>(bsum, NB);
  scan3_k<<<NB, 1024, 0, stream>>>(off, bsum, Nn);
  hipMemsetAsync(cnt, 0, (size_t)Nn*4, stream);
  scatter_k<<<ebk, THREADS, 0, stream>>>(ei, off, cnt, csr, csrd, Ee, ET);

  // dtype prep + fused-alpha B-columns + graph boundaries
  convf2b_k<<<(Nn*32 + THREADS-1)/THREADS, THREADS, 0, stream>>>((const float4*)x, (uint2*)bufA, Nn*32);
  wt_k<<<(128*192 + THREADS-1)/THREADS, THREADS, 0, stream>>>(W1, WT1, 128, 192);
  wt_k<<<(192*96  + THREADS-1)/THREADS, THREADS, 0, stream>>>(W2, WT2, 192, 96);
  wt_k<<<(96*48   + THREADS-1)/THREADS, THREADS, 0, stream>>>(W3, WT3, 96, 48);
  va_k<<<(6*128 + THREADS-1)/THREADS, THREADS, 0, stream>>>(W1, as1, ad1, WT1, 128, 64, 192);
  va_k<<<(6*192 + THREADS-1)/THREADS, THREADS, 0, stream>>>(W2, as2, ad2, WT2, 192, 32, 96);
  va_k<<<(6*96  + THREADS-1)/THREADS, THREADS, 0, stream>>>(W3, as3, ad3, WT3, 96, 16, 48);
  gboff_k<<<(Gg + 1 + THREADS-1)/THREADS, THREADS, 0, stream>>>(batch, goff, Nn, Gg);

  int nRT = Nn / 16;                 // 6250 row tiles
  int gx  = (nRT + 3) / 4;           // 4 waves/block
  int gb1 = (Nn + 3) / 4;            // GRP=64: 1 node/wave
  int gb2 = (Nn + 7) / 8;            // GRP=32: 2 nodes/wave
  int gb3 = (Nn + 15) / 16;          // GRP=16: 4 nodes/wave

  // layer 1: 128 -> 3x64
  gemm_mfma_k<128,192><<<gx, 256, 0, stream>>>(bufA, WT1, bufH, aS4, aD4, nRT);
  hipMemsetAsync(den4, 0, (size_t)Nn*16, stream);
  wgt_k<<<ebk, THREADS, 0, stream>>>(csr, csrd, aS4, aD4, wbuf, den4, ET);
  agg_k<192,6,64><<<gb1, 256, 0, stream>>>(off, csr, bufH, wbuf, den4, b1, nullptr, bufA, Nn, 1);
  // layer 2: 192 -> 3x32
  gemm_mfma_k<192,96><<<gx, 256, 0, stream>>>(bufA, WT2, bufH, aS4, aD4, nRT);
  hipMemsetAsync(den4, 0, (size_t)Nn*16, stream);
  wgt_k<<<ebk, THREADS, 0, stream>>>(csr, csrd, aS4, aD4, wbuf, den4, ET);
  agg_k<96,5,32><<<gb2, 256, 0, stream>>>(off, csr, bufH, wbuf, den4, b2, nullptr, bufA, Nn, 1);
  // layer 3: 96 -> 3x16 (no ELU)
  gemm_mfma_k<96,48><<<gx, 256, 0, stream>>>(bufA, WT3, bufH, aS4, aD4, nRT);
  hipMemsetAsync(den4, 0, (size_t)Nn*16, stream);
  wgt_k<<<ebk, THREADS, 0, stream>>>(csr, csrd, aS4, aD4, wbuf, den4, ET);
  agg_k<48,4,16><<<gb3, 256, 0, stream>>>(off, csr, bufH, wbuf, den4, b3, bufO, nullptr, Nn, 0);

  // fused mean pool + relu + linear + sigmoid + BCE loss
  hipMemsetAsync(lossAcc, 0, 4, stream);
  pool_logits_k<<<(Gg + 3)/4, 256, 0, stream>>>(bufO, goff, Wl, bl, y, outp, lossAcc, Gg);
  fin_k<<<1, 1, 0, stream>>>(lossAcc, outp, Gg);
}

// Round 10
// 813.807 us; speedup vs baseline: 1.9717x; 1.9717x over previous
//
#include <hip/hip_runtime.h>
#include <hip/hip_bf16.h>

#define THREADS 256
typedef __hip_bfloat16 bf16;

typedef __bf16 v8bf __attribute__((ext_vector_type(8)));
typedef float  v4f  __attribute__((ext_vector_type(4)));

__device__ __forceinline__ float bfl(unsigned u){ return __uint_as_float(u << 16); }
__device__ __forceinline__ float bfh(unsigned u){ return __uint_as_float(u & 0xffff0000u); }

// ---------------- CSR build (group edges by destination) ----------------
__global__ void hist_k(const int* __restrict__ ei, int* __restrict__ cnt, int E, int ET){
  int i = blockIdx.x*THREADS + threadIdx.x;
  if (i >= ET) return;
  int d = (i < E) ? ei[E + i] : (i - E);   // self-loops appended
  atomicAdd(&cnt[d], 1);
}

__global__ void scan1_k(const int* __restrict__ deg, int* __restrict__ off,
                        int* __restrict__ bsum, int n){
  __shared__ int sh[1024];
  int i = blockIdx.x*1024 + threadIdx.x;
  int v = (i < n) ? deg[i] : 0;
  sh[threadIdx.x] = v;
  __syncthreads();
  for (int s = 1; s < 1024; s <<= 1){
    int t = (threadIdx.x >= s) ? sh[threadIdx.x - s] : 0;
    __syncthreads();
    sh[threadIdx.x] += t;
    __syncthreads();
  }
  if (i < n) off[i+1] = sh[threadIdx.x];
  if (threadIdx.x == 1023) bsum[blockIdx.x] = sh[1023];
}

__global__ void scan2_k(int* __restrict__ bsum, int nb){
  __shared__ int sh[256];
  int v = (threadIdx.x < nb) ? bsum[threadIdx.x] : 0;
  sh[threadIdx.x] = v;
  __syncthreads();
  for (int s = 1; s < 256; s <<= 1){
    int t = (threadIdx.x >= s) ? sh[threadIdx.x - s] : 0;
    __syncthreads();
    sh[threadIdx.x] += t;
    __syncthreads();
  }
  if (threadIdx.x < nb) bsum[threadIdx.x] = sh[threadIdx.x] - v;  // exclusive
}

__global__ void scan3_k(int* __restrict__ off, const int* __restrict__ bsum, int n){
  int i = blockIdx.x*1024 + threadIdx.x;
  if (i < n) off[i+1] += bsum[blockIdx.x];
  if (i == 0) off[0] = 0;
}

__global__ void scatter_k(const int* __restrict__ ei, const int* __restrict__ off,
                          int* __restrict__ cur, int* __restrict__ csr,
                          int* __restrict__ csrd, int E, int ET){
  int i = blockIdx.x*THREADS + threadIdx.x;
  if (i >= ET) return;
  int s, d;
  if (i < E){ s = ei[i]; d = ei[E+i]; } else { s = i - E; d = i - E; }
  int p = off[d] + atomicAdd(&cur[d], 1);
  csr[p] = s;
  csrd[p] = d;
}

// ---------------- dtype prep ----------------
__global__ void convf2b_k(const float4* __restrict__ in, uint2* __restrict__ out, int n4){
  int i = blockIdx.x*THREADS + threadIdx.x;
  if (i >= n4) return;
  float4 v = in[i];
  union { bf16 h[4]; uint2 u; } cv;
  cv.h[0] = __float2bfloat16(v.x); cv.h[1] = __float2bfloat16(v.y);
  cv.h[2] = __float2bfloat16(v.z); cv.h[3] = __float2bfloat16(v.w);
  out[i] = cv.u;
}

// WT[c*K + k] = bf16(W[k*COUT + c])
__global__ void wt_k(const float* __restrict__ W, bf16* __restrict__ WT, int K, int COUT){
  int i = blockIdx.x*THREADS + threadIdx.x;
  if (i >= K*COUT) return;
  int k = i / COUT, c = i - k*COUT;
  WT[(size_t)c*K + k] = __float2bfloat16(W[i]);
}

// extra B-columns for fused alpha: WTX rows COUT..COUT+2 = W_h @ as_h, COUT+3..+5 = W_h @ ad_h
__global__ void va_k(const float* __restrict__ W, const float* __restrict__ as,
                     const float* __restrict__ ad, bf16* __restrict__ WTX,
                     int K, int C, int COUT){
  int i = blockIdx.x*THREADS + threadIdx.x;
  if (i >= 6*K) return;
  int k = i % K, c6 = i / K;
  int h = (c6 < 3) ? c6 : c6 - 3;
  const float* a = ((c6 < 3) ? as : ad) + h*C;
  const float* wp = W + (size_t)k*COUT + h*C;
  float s = 0.f;
  for (int cc = 0; cc < C; cc++) s += wp[cc]*a[cc];
  WTX[(size_t)(COUT + c6)*K + k] = __float2bfloat16(s);
}

// ---------------- MFMA GEMM fused with alpha: C = A@B, aS/aD from extra tile ----
template<int K, int COUT>
__global__ void __launch_bounds__(256) gemm_mfma_k(
    const bf16* __restrict__ A, const bf16* __restrict__ BT,
    bf16* __restrict__ C, float* __restrict__ aS4, float* __restrict__ aD4,
    int nRowTiles)
{
  int wave = threadIdx.x >> 6, lane = threadIdx.x & 63;
  int rt = blockIdx.x*4 + wave;
  if (rt >= nRowTiles) return;
  int half = lane & 15;
  int quad = lane >> 4;
  const __bf16* aBase = (const __bf16*)A + (size_t)(rt*16 + half)*K + quad*8;
  v8bf aF[K/32];
  #pragma unroll
  for (int kk = 0; kk < K/32; kk++) aF[kk] = *(const v8bf*)(aBase + kk*32);
  #pragma unroll
  for (int cb = 0; cb < COUT + 16; cb += 16){
    const __bf16* bBase = (const __bf16*)BT + (size_t)(cb + half)*K + quad*8;
    v4f acc = {0.f, 0.f, 0.f, 0.f};
    #pragma unroll
    for (int kk = 0; kk < K/32; kk++)
      acc = __builtin_amdgcn_mfma_f32_16x16x32_bf16(aF[kk], *(const v8bf*)(bBase + kk*32), acc, 0, 0, 0);
    int orow = rt*16 + quad*4;                 // D: col=lane&15, row=quad*4+reg
    if (cb < COUT){
      bf16* cp = C + (size_t)orow*COUT + cb + half;
      #pragma unroll
      for (int r = 0; r < 4; r++)
        cp[(size_t)r*COUT] = __float2bfloat16(acc[r]);
    } else if (half < 6){
      #pragma unroll
      for (int r = 0; r < 4; r++){
        int row = orow + r;
        if (half < 3) aS4[row*4 + half]     = acc[r];
        else          aD4[row*4 + half - 3] = acc[r];
      }
    }
  }
}

// ---------------- per-edge softmax numerators (edge-parallel, no atomics) ----------------
__global__ void wgt_k(const int* __restrict__ csr, const int* __restrict__ csrd,
                      const float* __restrict__ aS4, const float* __restrict__ aD4,
                      float* __restrict__ wbuf, int ET)
{
  int i = blockIdx.x*THREADS + threadIdx.x;
  if (i >= ET) return;
  int s = csr[i], d = csrd[i];
  const float4 as = *(const float4*)(aS4 + 4*s);
  const float4 ad = *(const float4*)(aD4 + 4*d);
  float x0 = as.x + ad.x; x0 = (x0 > 0.f) ? x0 : 0.2f*x0;
  float x1 = as.y + ad.y; x1 = (x1 > 0.f) ? x1 : 0.2f*x1;
  float x2 = as.z + ad.z; x2 = (x2 > 0.f) ? x2 : 0.2f*x2;
  float4 w = {__expf(x0), __expf(x1), __expf(x2), 0.f};
  *(float4*)(wbuf + 4*i) = w;
}

// ---------------- per-(node,head) denominators: serial sum over contiguous CSR slice ---
__global__ void den_k(const int* __restrict__ off, const float* __restrict__ wbuf,
                      float* __restrict__ den4, int n)
{
  int idx = blockIdx.x*THREADS + threadIdx.x;
  if (idx >= n*3) return;
  int node = idx / 3, h = idx - node*3;
  int e0 = off[node], e1 = off[node+1];
  const float* wp = wbuf + h;
  float s0 = 0.f, s1 = 0.f, s2 = 0.f, s3 = 0.f;
  int e = e0;
  for (; e + 4 <= e1; e += 4){
    s0 += wp[4*(e+0)]; s1 += wp[4*(e+1)]; s2 += wp[4*(e+2)]; s3 += wp[4*(e+3)];
  }
  for (; e < e1; e++) s0 += wp[4*e];
  den4[4*node + h] = (s0 + s1) + (s2 + s3);
}

// ---------------- weighted aggregation (GRP lanes per dst node) ----------------
// Denominator precomputed in den4; per-edge: csr dword + own-head w dword + 8B gather + 4 FMA.
template<int HC, int CSH, int GRP>
__global__ void __launch_bounds__(256) agg_k(
    const int* __restrict__ off, const int* __restrict__ csr,
    const bf16* __restrict__ hbuf, const float* __restrict__ wbuf,
    const float* __restrict__ den4, const float* __restrict__ bias,
    float* __restrict__ outF, bf16* __restrict__ outB,
    int n, int doElu)
{
  constexpr int NPW = 64 / GRP;
  int lane = threadIdx.x & 63;
  int wv = (blockIdx.x*256 + threadIdx.x) >> 6;
  int q = lane % GRP;
  int node = wv*NPW + lane/GRP;
  if (node >= n) return;
  const bool act = q < HC/4;
  if (!act) return;
  int e0 = off[node], e1 = off[node+1];
  const int hq = (4*q) >> CSH;               // head of this lane's 4 channels
  float inv = 1.f / (den4[4*node + hq] + 1e-16f);
  float a0 = 0.f, a1 = 0.f, a2 = 0.f, a3 = 0.f;
  const size_t hoff = 4*q;
  const float* wp = wbuf + hq;
  int e = e0;
  for (; e + 4 <= e1; e += 4){
    int s0 = csr[e+0], s1 = csr[e+1], s2 = csr[e+2], s3 = csr[e+3];
    float w0 = wp[4*(e+0)];
    float w1 = wp[4*(e+1)];
    float w2 = wp[4*(e+2)];
    float w3 = wp[4*(e+3)];
    uint2 u0 = *(const uint2*)(hbuf + (size_t)s0*HC + hoff);
    uint2 u1 = *(const uint2*)(hbuf + (size_t)s1*HC + hoff);
    uint2 u2 = *(const uint2*)(hbuf + (size_t)s2*HC + hoff);
    uint2 u3 = *(const uint2*)(hbuf + (size_t)s3*HC + hoff);
    a0 += w0*bfl(u0.x); a1 += w0*bfh(u0.x); a2 += w0*bfl(u0.y); a3 += w0*bfh(u0.y);
    a0 += w1*bfl(u1.x); a1 += w1*bfh(u1.x); a2 += w1*bfl(u1.y); a3 += w1*bfh(u1.y);
    a0 += w2*bfl(u2.x); a1 += w2*bfh(u2.x); a2 += w2*bfl(u2.y); a3 += w2*bfh(u2.y);
    a0 += w3*bfl(u3.x); a1 += w3*bfh(u3.x); a2 += w3*bfl(u3.y); a3 += w3*bfh(u3.y);
  }
  for (; e < e1; e++){
    int s = csr[e];
    float w = wp[4*e];
    uint2 u = *(const uint2*)(hbuf + (size_t)s*HC + hoff);
    a0 += w*bfl(u.x); a1 += w*bfh(u.x); a2 += w*bfl(u.y); a3 += w*bfh(u.y);
  }
  {
    const float4 b = *(const float4*)(bias + 4*q);
    float r0 = a0*inv + b.x, r1 = a1*inv + b.y, r2 = a2*inv + b.z, r3 = a3*inv + b.w;
    if (doElu){
      r0 = (r0 > 0.f) ? r0 : (__expf(r0) - 1.f);
      r1 = (r1 > 0.f) ? r1 : (__expf(r1) - 1.f);
      r2 = (r2 > 0.f) ? r2 : (__expf(r2) - 1.f);
      r3 = (r3 > 0.f) ? r3 : (__expf(r3) - 1.f);
    }
    if (outF){
      float4 o = {r0, r1, r2, r3};
      *(float4*)(outF + (size_t)node*HC + 4*q) = o;
    }
    if (outB){
      union { bf16 h[4]; uint2 u; } cv;
      cv.h[0] = __float2bfloat16(r0); cv.h[1] = __float2bfloat16(r1);
      cv.h[2] = __float2bfloat16(r2); cv.h[3] = __float2bfloat16(r3);
      *(uint2*)(outB + (size_t)node*HC + 4*q) = cv.u;
    }
  }
}

// ---------------- graph boundaries via binary search on sorted batch ----------------
__global__ void gboff_k(const int* __restrict__ batch, int* __restrict__ goff, int n, int G){
  int g = blockIdx.x*THREADS + threadIdx.x;
  if (g > G) return;
  if (g == G){ goff[G] = n; return; }
  int lo = 0, hi = n;
  while (lo < hi){ int mid = (lo + hi) >> 1; if (batch[mid] < g) lo = mid + 1; else hi = mid; }
  goff[g] = lo;
}

// ---------------- fused mean-pool + relu + linear + sigmoid + BCE (wave per graph) ---
__global__ void __launch_bounds__(256) pool_logits_k(
    const float* __restrict__ h3, const int* __restrict__ goff,
    const float* __restrict__ Wl, const float* __restrict__ bl,
    const float* __restrict__ y, float* __restrict__ outp,
    float* __restrict__ lossAcc, int G)
{
  int lane = threadIdx.x & 63;
  int g = (blockIdx.x*256 + threadIdx.x) >> 6;
  if (g >= G) return;
  int n0 = goff[g], n1 = goff[g+1];
  int cnt = n1 - n0;
  float acc = 0.f, acc2 = 0.f, wl = 0.f;
  if (lane < 48){
    wl = Wl[lane];
    const float* p = h3 + (size_t)n0*48 + lane;
    int i = 0;
    for (; i + 2 <= cnt; i += 2){ acc += p[(size_t)i*48]; acc2 += p[(size_t)(i+1)*48]; }
    if (i < cnt) acc += p[(size_t)i*48];
    acc += acc2;
  }
  float inv = 1.f / fmaxf((float)cnt, 1.f);
  float v = fmaxf(acc*inv, 0.f) * wl;
  for (int o = 32; o > 0; o >>= 1) v += __shfl_down(v, o);
  if (lane == 0){
    float logit = v + bl[0];
    outp[g] = 1.f / (1.f + __expf(-logit));
    float t = y[g];
    float sp = (logit > 0.f) ? (logit + log1pf(__expf(-logit))) : log1pf(__expf(logit));
    atomicAdd(lossAcc, sp - t*logit);
  }
}

__global__ void fin_k(const float* __restrict__ lossAcc, float* __restrict__ outp, int gtot){
  outp[gtot] = lossAcc[0] / (float)gtot;
}

// ---------------- launch ----------------
extern "C" void kernel_launch(void* const* d_in, const int* in_sizes, int n_in,
                              void* d_out, int out_size, void* d_ws, size_t ws_size,
                              hipStream_t stream)
{
  (void)n_in; (void)out_size; (void)ws_size;
  const float* x    = (const float*)d_in[0];
  const float* y    = (const float*)d_in[1];
  const int*  ei    = (const int*)d_in[2];
  const int*  batch = (const int*)d_in[3];
  const float* W1 = (const float*)d_in[4];
  const float* as1= (const float*)d_in[5];
  const float* ad1= (const float*)d_in[6];
  const float* b1 = (const float*)d_in[7];
  const float* W2 = (const float*)d_in[8];
  const float* as2= (const float*)d_in[9];
  const float* ad2= (const float*)d_in[10];
  const float* b2 = (const float*)d_in[11];
  const float* W3 = (const float*)d_in[12];
  const float* as3= (const float*)d_in[13];
  const float* ad3= (const float*)d_in[14];
  const float* b3 = (const float*)d_in[15];
  const float* Wl = (const float*)d_in[16];
  const float* bl = (const float*)d_in[17];
  float* outp = (float*)d_out;

  int Nn = in_sizes[0] / 128;   // 100000 (multiple of 16)
  int Gg = in_sizes[1];
  int Ee = in_sizes[2] / 2;
  int ET = Ee + Nn;

  char* p = (char*)d_ws;
  auto carve = [&](size_t bytes) -> void* {
    void* r = (void*)p; p += (bytes + 255) & ~(size_t)255; return r;
  };
  int*   off     = (int*)  carve((size_t)(Nn+1)*4);
  int*   cnt     = (int*)  carve((size_t)Nn*4);
  int*   csr     = (int*)  carve((size_t)ET*4);
  int*   csrd    = (int*)  carve((size_t)ET*4);
  float* wbuf    = (float*)carve((size_t)ET*4*4);
  int*   bsum    = (int*)  carve(256*4);
  float* aS4     = (float*)carve((size_t)Nn*4*4);
  float* aD4     = (float*)carve((size_t)Nn*4*4);
  float* den4    = (float*)carve((size_t)Nn*4*4);
  int*   goff    = (int*)  carve((size_t)(Gg+1)*4);
  float* lossAcc = (float*)carve(4);
  bf16*  WT1     = (bf16*) carve((size_t)(192+16)*128*2);
  bf16*  WT2     = (bf16*) carve((size_t)(96+16)*192*2);
  bf16*  WT3     = (bf16*) carve((size_t)(48+16)*96*2);
  bf16*  bufH    = (bf16*) carve((size_t)Nn*192*2);   // GEMM out (h), agg in
  bf16*  bufA    = (bf16*) carve((size_t)Nn*192*2);   // GEMM A-operand
  // layer-3 f32 out for pooling: alias into the unused tail of bufH's region
  float* bufO    = (float*)((char*)bufH + ((size_t)Nn*96 + 255 & ~(size_t)255));

  int NB = (Nn + 1023) / 1024;
  int ebk = (ET + THREADS - 1) / THREADS;
  int nb3 = (Nn*3 + THREADS - 1) / THREADS;

  // CSR by destination
  hipMemsetAsync(cnt, 0, (size_t)Nn*4, stream);
  hist_k<<<ebk, THREADS, 0, stream>>>(ei, cnt, Ee, ET);
  scan1_k<<<NB, 1024, 0, stream>>>(cnt, off, bsum, Nn);
  scan2_k<<<1, 256, 0, stream>>>(bsum, NB);
  scan3_k<<<NB, 1024, 0, stream>>>(off, bsum, Nn);
  hipMemsetAsync(cnt, 0, (size_t)Nn*4, stream);
  scatter_k<<<ebk, THREADS, 0, stream>>>(ei, off, cnt, csr, csrd, Ee, ET);

  // dtype prep + fused-alpha B-columns + graph boundaries
  convf2b_k<<<(Nn*32 + THREADS-1)/THREADS, THREADS, 0, stream>>>((const float4*)x, (uint2*)bufA, Nn*32);
  wt_k<<<(128*192 + THREADS-1)/THREADS, THREADS, 0, stream>>>(W1, WT1, 128, 192);
  wt_k<<<(192*96  + THREADS-1)/THREADS, THREADS, 0, stream>>>(W2, WT2, 192, 96);
  wt_k<<<(96*48   + THREADS-1)/THREADS, THREADS, 0, stream>>>(W3, WT3, 96, 48);
  va_k<<<(6*128 + THREADS-1)/THREADS, THREADS, 0, stream>>>(W1, as1, ad1, WT1, 128, 64, 192);
  va_k<<<(6*192 + THREADS-1)/THREADS, THREADS, 0, stream>>>(W2, as2, ad2, WT2, 192, 32, 96);
  va_k<<<(6*96  + THREADS-1)/THREADS, THREADS, 0, stream>>>(W3, as3, ad3, WT3, 96, 16, 48);
  gboff_k<<<(Gg + 1 + THREADS-1)/THREADS, THREADS, 0, stream>>>(batch, goff, Nn, Gg);

  int nRT = Nn / 16;                 // 6250 row tiles
  int gx  = (nRT + 3) / 4;           // 4 waves/block
  int gb1 = (Nn + 3) / 4;            // GRP=64: 1 node/wave
  int gb2 = (Nn + 7) / 8;            // GRP=32: 2 nodes/wave
  int gb3 = (Nn + 15) / 16;          // GRP=16: 4 nodes/wave

  // layer 1: 128 -> 3x64
  gemm_mfma_k<128,192><<<gx, 256, 0, stream>>>(bufA, WT1, bufH, aS4, aD4, nRT);
  wgt_k<<<ebk, THREADS, 0, stream>>>(csr, csrd, aS4, aD4, wbuf, ET);
  den_k<<<nb3, THREADS, 0, stream>>>(off, wbuf, den4, Nn);
  agg_k<192,6,64><<<gb1, 256, 0, stream>>>(off, csr, bufH, wbuf, den4, b1, nullptr, bufA, Nn, 1);
  // layer 2: 192 -> 3x32
  gemm_mfma_k<192,96><<<gx, 256, 0, stream>>>(bufA, WT2, bufH, aS4, aD4, nRT);
  wgt_k<<<ebk, THREADS, 0, stream>>>(csr, csrd, aS4, aD4, wbuf, ET);
  den_k<<<nb3, THREADS, 0, stream>>>(off, wbuf, den4, Nn);
  agg_k<96,5,32><<<gb2, 256, 0, stream>>>(off, csr, bufH, wbuf, den4, b2, nullptr, bufA, Nn, 1);
  // layer 3: 96 -> 3x16 (no ELU)
  gemm_mfma_k<96,48><<<gx, 256, 0, stream>>>(bufA, WT3, bufH, aS4, aD4, nRT);
  wgt_k<<<ebk, THREADS, 0, stream>>>(csr, csrd, aS4, aD4, wbuf, ET);
  den_k<<<nb3, THREADS, 0, stream>>>(off, wbuf, den4, Nn);
  agg_k<48,4,16><<<gb3, 256, 0, stream>>>(off, csr, bufH, wbuf, den4, b3, bufO, nullptr, Nn, 0);

  // fused mean pool + relu + linear + sigmoid + BCE loss
  hipMemsetAsync(lossAcc, 0, 4, stream);
  pool_logits_k<<<(Gg + 3)/4, 256, 0, stream>>>(bufO, goff, Wl, bl, y, outp, lossAcc, Gg);
  fin_k<<<1, 1, 0, stream>>>(lossAcc, outp, Gg);
}

// Round 11
// 721.226 us; speedup vs baseline: 2.2247x; 1.1284x over previous
//
#include <hip/hip_runtime.h>
#include <hip/hip_bf16.h>

#define THREADS 256
typedef __hip_bfloat16 bf16;

typedef __bf16 v8bf __attribute__((ext_vector_type(8)));
typedef float  v4f  __attribute__((ext_vector_type(4)));

__device__ __forceinline__ float bfl(unsigned u){ return __uint_as_float(u << 16); }
__device__ __forceinline__ float bfh(unsigned u){ return __uint_as_float(u & 0xffff0000u); }

// ---------------- CSR build (group edges by destination) ----------------
// hist also records each edge's rank within its destination bucket -> scatter needs no atomics.
__global__ void hist_k(const int* __restrict__ ei, int* __restrict__ cnt,
                       int* __restrict__ rank, int E, int ET){
  int i = blockIdx.x*THREADS + threadIdx.x;
  if (i >= ET) return;
  int d = (i < E) ? ei[E + i] : (i - E);   // self-loops appended
  rank[i] = atomicAdd(&cnt[d], 1);
}

__global__ void scan1_k(const int* __restrict__ deg, int* __restrict__ off,
                        int* __restrict__ bsum, int n){
  __shared__ int sh[1024];
  int i = blockIdx.x*1024 + threadIdx.x;
  int v = (i < n) ? deg[i] : 0;
  sh[threadIdx.x] = v;
  __syncthreads();
  for (int s = 1; s < 1024; s <<= 1){
    int t = (threadIdx.x >= s) ? sh[threadIdx.x - s] : 0;
    __syncthreads();
    sh[threadIdx.x] += t;
    __syncthreads();
  }
  if (i < n) off[i+1] = sh[threadIdx.x];
  if (threadIdx.x == 1023) bsum[blockIdx.x] = sh[1023];
}

__global__ void scan2_k(int* __restrict__ bsum, int nb){
  __shared__ int sh[256];
  int v = (threadIdx.x < nb) ? bsum[threadIdx.x] : 0;
  sh[threadIdx.x] = v;
  __syncthreads();
  for (int s = 1; s < 256; s <<= 1){
    int t = (threadIdx.x >= s) ? sh[threadIdx.x - s] : 0;
    __syncthreads();
    sh[threadIdx.x] += t;
    __syncthreads();
  }
  if (threadIdx.x < nb) bsum[threadIdx.x] = sh[threadIdx.x] - v;  // exclusive
}

__global__ void scan3_k(int* __restrict__ off, const int* __restrict__ bsum, int n){
  int i = blockIdx.x*1024 + threadIdx.x;
  if (i < n) off[i+1] += bsum[blockIdx.x];
  if (i == 0) off[0] = 0;
}

__global__ void scatter_k(const int* __restrict__ ei, const int* __restrict__ off,
                          const int* __restrict__ rank, int* __restrict__ csr,
                          int E, int ET){
  int i = blockIdx.x*THREADS + threadIdx.x;
  if (i >= ET) return;
  int s, d;
  if (i < E){ s = ei[i]; d = ei[E+i]; } else { s = i - E; d = i - E; }
  csr[off[d] + rank[i]] = s;
}

// ---------------- dtype prep ----------------
__global__ void convf2b_k(const float4* __restrict__ in, uint2* __restrict__ out, int n4){
  int i = blockIdx.x*THREADS + threadIdx.x;
  if (i >= n4) return;
  float4 v = in[i];
  union { bf16 h[4]; uint2 u; } cv;
  cv.h[0] = __float2bfloat16(v.x); cv.h[1] = __float2bfloat16(v.y);
  cv.h[2] = __float2bfloat16(v.z); cv.h[3] = __float2bfloat16(v.w);
  out[i] = cv.u;
}

// WT[c*K + k] = bf16(W[k*COUT + c])
__global__ void wt_k(const float* __restrict__ W, bf16* __restrict__ WT, int K, int COUT){
  int i = blockIdx.x*THREADS + threadIdx.x;
  if (i >= K*COUT) return;
  int k = i / COUT, c = i - k*COUT;
  WT[(size_t)c*K + k] = __float2bfloat16(W[i]);
}

// extra B-columns for fused alpha: WTX rows COUT..COUT+2 = W_h @ as_h, COUT+3..+5 = W_h @ ad_h
__global__ void va_k(const float* __restrict__ W, const float* __restrict__ as,
                     const float* __restrict__ ad, bf16* __restrict__ WTX,
                     int K, int C, int COUT){
  int i = blockIdx.x*THREADS + threadIdx.x;
  if (i >= 6*K) return;
  int k = i % K, c6 = i / K;
  int h = (c6 < 3) ? c6 : c6 - 3;
  const float* a = ((c6 < 3) ? as : ad) + h*C;
  const float* wp = W + (size_t)k*COUT + h*C;
  float s = 0.f;
  for (int cc = 0; cc < C; cc++) s += wp[cc]*a[cc];
  WTX[(size_t)(COUT + c6)*K + k] = __float2bfloat16(s);
}

// ---------------- MFMA GEMM fused with alpha: C = A@B, aS/aD from extra tile ----
template<int K, int COUT>
__global__ void __launch_bounds__(256) gemm_mfma_k(
    const bf16* __restrict__ A, const bf16* __restrict__ BT,
    bf16* __restrict__ C, float* __restrict__ aS4, float* __restrict__ aD4,
    int nRowTiles)
{
  int wave = threadIdx.x >> 6, lane = threadIdx.x & 63;
  int rt = blockIdx.x*4 + wave;
  if (rt >= nRowTiles) return;
  int half = lane & 15;
  int quad = lane >> 4;
  const __bf16* aBase = (const __bf16*)A + (size_t)(rt*16 + half)*K + quad*8;
  v8bf aF[K/32];
  #pragma unroll
  for (int kk = 0; kk < K/32; kk++) aF[kk] = *(const v8bf*)(aBase + kk*32);
  #pragma unroll
  for (int cb = 0; cb < COUT + 16; cb += 16){
    const __bf16* bBase = (const __bf16*)BT + (size_t)(cb + half)*K + quad*8;
    v4f acc = {0.f, 0.f, 0.f, 0.f};
    #pragma unroll
    for (int kk = 0; kk < K/32; kk++)
      acc = __builtin_amdgcn_mfma_f32_16x16x32_bf16(aF[kk], *(const v8bf*)(bBase + kk*32), acc, 0, 0, 0);
    int orow = rt*16 + quad*4;                 // D: col=lane&15, row=quad*4+reg
    if (cb < COUT){
      bf16* cp = C + (size_t)orow*COUT + cb + half;
      #pragma unroll
      for (int r = 0; r < 4; r++)
        cp[(size_t)r*COUT] = __float2bfloat16(acc[r]);
    } else if (half < 6){
      #pragma unroll
      for (int r = 0; r < 4; r++){
        int row = orow + r;
        if (half < 3) aS4[row*4 + half]     = acc[r];
        else          aD4[row*4 + half - 3] = acc[r];
      }
    }
  }
}

// ---------------- per-edge weights + per-node denominators (thread per dst node) -----
__global__ void wgtden_k(const int* __restrict__ off, const int* __restrict__ csr,
                         const float* __restrict__ aS4, const float* __restrict__ aD4,
                         float* __restrict__ wbuf, float* __restrict__ den4, int n)
{
  int node = blockIdx.x*THREADS + threadIdx.x;
  if (node >= n) return;
  int e0 = off[node], e1 = off[node+1];
  const float4 ad = *(const float4*)(aD4 + 4*node);
  float d0 = 0.f, d1 = 0.f, d2 = 0.f;
  int e = e0;
  for (; e + 4 <= e1; e += 4){
    int s0 = csr[e+0], s1 = csr[e+1], s2 = csr[e+2], s3 = csr[e+3];
    float4 A = *(const float4*)(aS4 + 4*s0);
    float4 B = *(const float4*)(aS4 + 4*s1);
    float4 Cc= *(const float4*)(aS4 + 4*s2);
    float4 D = *(const float4*)(aS4 + 4*s3);
    float x; float4 w;
    x = A.x + ad.x; x = (x > 0.f) ? x : 0.2f*x; w.x = __expf(x);
    x = A.y + ad.y; x = (x > 0.f) ? x : 0.2f*x; w.y = __expf(x);
    x = A.z + ad.z; x = (x > 0.f) ? x : 0.2f*x; w.z = __expf(x);
    w.w = 0.f; d0 += w.x; d1 += w.y; d2 += w.z;
    *(float4*)(wbuf + 4*(e+0)) = w;
    x = B.x + ad.x; x = (x > 0.f) ? x : 0.2f*x; w.x = __expf(x);
    x = B.y + ad.y; x = (x > 0.f) ? x : 0.2f*x; w.y = __expf(x);
    x = B.z + ad.z; x = (x > 0.f) ? x : 0.2f*x; w.z = __expf(x);
    d0 += w.x; d1 += w.y; d2 += w.z;
    *(float4*)(wbuf + 4*(e+1)) = w;
    x = Cc.x + ad.x; x = (x > 0.f) ? x : 0.2f*x; w.x = __expf(x);
    x = Cc.y + ad.y; x = (x > 0.f) ? x : 0.2f*x; w.y = __expf(x);
    x = Cc.z + ad.z; x = (x > 0.f) ? x : 0.2f*x; w.z = __expf(x);
    d0 += w.x; d1 += w.y; d2 += w.z;
    *(float4*)(wbuf + 4*(e+2)) = w;
    x = D.x + ad.x; x = (x > 0.f) ? x : 0.2f*x; w.x = __expf(x);
    x = D.y + ad.y; x = (x > 0.f) ? x : 0.2f*x; w.y = __expf(x);
    x = D.z + ad.z; x = (x > 0.f) ? x : 0.2f*x; w.z = __expf(x);
    d0 += w.x; d1 += w.y; d2 += w.z;
    *(float4*)(wbuf + 4*(e+3)) = w;
  }
  for (; e < e1; e++){
    int s = csr[e];
    float4 A = *(const float4*)(aS4 + 4*s);
    float x; float4 w;
    x = A.x + ad.x; x = (x > 0.f) ? x : 0.2f*x; w.x = __expf(x);
    x = A.y + ad.y; x = (x > 0.f) ? x : 0.2f*x; w.y = __expf(x);
    x = A.z + ad.z; x = (x > 0.f) ? x : 0.2f*x; w.z = __expf(x);
    w.w = 0.f; d0 += w.x; d1 += w.y; d2 += w.z;
    *(float4*)(wbuf + 4*e) = w;
  }
  float4 dd = {d0, d1, d2, 0.f};
  *(float4*)(den4 + 4*node) = dd;
}

// ---------------- weighted aggregation (GRP lanes per dst node) ----------------
// Denominator precomputed in den4; per-edge: csr dword + own-head w dword + 8B gather + 4 FMA.
template<int HC, int CSH, int GRP>
__global__ void __launch_bounds__(256) agg_k(
    const int* __restrict__ off, const int* __restrict__ csr,
    const bf16* __restrict__ hbuf, const float* __restrict__ wbuf,
    const float* __restrict__ den4, const float* __restrict__ bias,
    float* __restrict__ outF, bf16* __restrict__ outB,
    int n, int doElu)
{
  constexpr int NPW = 64 / GRP;
  int lane = threadIdx.x & 63;
  int wv = (blockIdx.x*256 + threadIdx.x) >> 6;
  int q = lane % GRP;
  int node = wv*NPW + lane/GRP;
  if (node >= n) return;
  const bool act = q < HC/4;
  if (!act) return;
  int e0 = off[node], e1 = off[node+1];
  const int hq = (4*q) >> CSH;               // head of this lane's 4 channels
  float inv = 1.f / (den4[4*node + hq] + 1e-16f);
  float a0 = 0.f, a1 = 0.f, a2 = 0.f, a3 = 0.f;
  const size_t hoff = 4*q;
  const float* wp = wbuf + hq;
  int e = e0;
  for (; e + 4 <= e1; e += 4){
    int s0 = csr[e+0], s1 = csr[e+1], s2 = csr[e+2], s3 = csr[e+3];
    float w0 = wp[4*(e+0)];
    float w1 = wp[4*(e+1)];
    float w2 = wp[4*(e+2)];
    float w3 = wp[4*(e+3)];
    uint2 u0 = *(const uint2*)(hbuf + (size_t)s0*HC + hoff);
    uint2 u1 = *(const uint2*)(hbuf + (size_t)s1*HC + hoff);
    uint2 u2 = *(const uint2*)(hbuf + (size_t)s2*HC + hoff);
    uint2 u3 = *(const uint2*)(hbuf + (size_t)s3*HC + hoff);
    a0 += w0*bfl(u0.x); a1 += w0*bfh(u0.x); a2 += w0*bfl(u0.y); a3 += w0*bfh(u0.y);
    a0 += w1*bfl(u1.x); a1 += w1*bfh(u1.x); a2 += w1*bfl(u1.y); a3 += w1*bfh(u1.y);
    a0 += w2*bfl(u2.x); a1 += w2*bfh(u2.x); a2 += w2*bfl(u2.y); a3 += w2*bfh(u2.y);
    a0 += w3*bfl(u3.x); a1 += w3*bfh(u3.x); a2 += w3*bfl(u3.y); a3 += w3*bfh(u3.y);
  }
  for (; e < e1; e++){
    int s = csr[e];
    float w = wp[4*e];
    uint2 u = *(const uint2*)(hbuf + (size_t)s*HC + hoff);
    a0 += w*bfl(u.x); a1 += w*bfh(u.x); a2 += w*bfl(u.y); a3 += w*bfh(u.y);
  }
  {
    const float4 b = *(const float4*)(bias + 4*q);
    float r0 = a0*inv + b.x, r1 = a1*inv + b.y, r2 = a2*inv + b.z, r3 = a3*inv + b.w;
    if (doElu){
      r0 = (r0 > 0.f) ? r0 : (__expf(r0) - 1.f);
      r1 = (r1 > 0.f) ? r1 : (__expf(r1) - 1.f);
      r2 = (r2 > 0.f) ? r2 : (__expf(r2) - 1.f);
      r3 = (r3 > 0.f) ? r3 : (__expf(r3) - 1.f);
    }
    if (outF){
      float4 o = {r0, r1, r2, r3};
      *(float4*)(outF + (size_t)node*HC + 4*q) = o;
    }
    if (outB){
      union { bf16 h[4]; uint2 u; } cv;
      cv.h[0] = __float2bfloat16(r0); cv.h[1] = __float2bfloat16(r1);
      cv.h[2] = __float2bfloat16(r2); cv.h[3] = __float2bfloat16(r3);
      *(uint2*)(outB + (size_t)node*HC + 4*q) = cv.u;
    }
  }
}

// ---------------- graph boundaries via binary search on sorted batch ----------------
__global__ void gboff_k(const int* __restrict__ batch, int* __restrict__ goff, int n, int G){
  int g = blockIdx.x*THREADS + threadIdx.x;
  if (g > G) return;
  if (g == G){ goff[G] = n; return; }
  int lo = 0, hi = n;
  while (lo < hi){ int mid = (lo + hi) >> 1; if (batch[mid] < g) lo = mid + 1; else hi = mid; }
  goff[g] = lo;
}

// ---------------- fused mean-pool + relu + linear + sigmoid + BCE (wave per graph) ---
__global__ void __launch_bounds__(256) pool_logits_k(
    const float* __restrict__ h3, const int* __restrict__ goff,
    const float* __restrict__ Wl, const float* __restrict__ bl,
    const float* __restrict__ y, float* __restrict__ outp,
    float* __restrict__ lossAcc, int G)
{
  int lane = threadIdx.x & 63;
  int g = (blockIdx.x*256 + threadIdx.x) >> 6;
  if (g >= G) return;
  int n0 = goff[g], n1 = goff[g+1];
  int cnt = n1 - n0;
  float acc = 0.f, acc2 = 0.f, wl = 0.f;
  if (lane < 48){
    wl = Wl[lane];
    const float* p = h3 + (size_t)n0*48 + lane;
    int i = 0;
    for (; i + 2 <= cnt; i += 2){ acc += p[(size_t)i*48]; acc2 += p[(size_t)(i+1)*48]; }
    if (i < cnt) acc += p[(size_t)i*48];
    acc += acc2;
  }
  float inv = 1.f / fmaxf((float)cnt, 1.f);
  float v = fmaxf(acc*inv, 0.f) * wl;
  for (int o = 32; o > 0; o >>= 1) v += __shfl_down(v, o);
  if (lane == 0){
    float logit = v + bl[0];
    outp[g] = 1.f / (1.f + __expf(-logit));
    float t = y[g];
    float sp = (logit > 0.f) ? (logit + log1pf(__expf(-logit))) : log1pf(__expf(logit));
    atomicAdd(lossAcc, sp - t*logit);
  }
}

__global__ void fin_k(const float* __restrict__ lossAcc, float* __restrict__ outp, int gtot){
  outp[gtot] = lossAcc[0] / (float)gtot;
}

// ---------------- launch ----------------
extern "C" void kernel_launch(void* const* d_in, const int* in_sizes, int n_in,
                              void* d_out, int out_size, void* d_ws, size_t ws_size,
                              hipStream_t stream)
{
  (void)n_in; (void)out_size; (void)ws_size;
  const float* x    = (const float*)d_in[0];
  const float* y    = (const float*)d_in[1];
  const int*  ei    = (const int*)d_in[2];
  const int*  batch = (const int*)d_in[3];
  const float* W1 = (const float*)d_in[4];
  const float* as1= (const float*)d_in[5];
  const float* ad1= (const float*)d_in[6];
  const float* b1 = (const float*)d_in[7];
  const float* W2 = (const float*)d_in[8];
  const float* as2= (const float*)d_in[9];
  const float* ad2= (const float*)d_in[10];
  const float* b2 = (const float*)d_in[11];
  const float* W3 = (const float*)d_in[12];
  const float* as3= (const float*)d_in[13];
  const float* ad3= (const float*)d_in[14];
  const float* b3 = (const float*)d_in[15];
  const float* Wl = (const float*)d_in[16];
  const float* bl = (const float*)d_in[17];
  float* outp = (float*)d_out;

  int Nn = in_sizes[0] / 128;   // 100000 (multiple of 16)
  int Gg = in_sizes[1];
  int Ee = in_sizes[2] / 2;
  int ET = Ee + Nn;

  char* p = (char*)d_ws;
  auto carve = [&](size_t bytes) -> void* {
    void* r = (void*)p; p += (bytes + 255) & ~(size_t)255; return r;
  };
  int*   off     = (int*)  carve((size_t)(Nn+1)*4);
  int*   cnt     = (int*)  carve((size_t)Nn*4);
  int*   csr     = (int*)  carve((size_t)ET*4);
  int*   rank    = (int*)  carve((size_t)ET*4);
  float* wbuf    = (float*)carve((size_t)ET*4*4);
  int*   bsum    = (int*)  carve(256*4);
  float* aS4     = (float*)carve((size_t)Nn*4*4);
  float* aD4     = (float*)carve((size_t)Nn*4*4);
  float* den4    = (float*)carve((size_t)Nn*4*4);
  int*   goff    = (int*)  carve((size_t)(Gg+1)*4);
  float* lossAcc = (float*)carve(4);
  bf16*  WT1     = (bf16*) carve((size_t)(192+16)*128*2);
  bf16*  WT2     = (bf16*) carve((size_t)(96+16)*192*2);
  bf16*  WT3     = (bf16*) carve((size_t)(48+16)*96*2);
  bf16*  bufH    = (bf16*) carve((size_t)Nn*192*2);   // GEMM out (h), agg in
  bf16*  bufA    = (bf16*) carve((size_t)Nn*192*2);   // GEMM A-operand
  // layer-3 f32 out for pooling: alias into the unused tail of bufH's region
  float* bufO    = (float*)((char*)bufH + ((size_t)Nn*96 + 255 & ~(size_t)255));

  int NB = (Nn + 1023) / 1024;
  int ebk = (ET + THREADS - 1) / THREADS;
  int nbk = (Nn + THREADS - 1) / THREADS;

  // CSR by destination (atomic-free scatter via rank)
  hipMemsetAsync(cnt, 0, (size_t)Nn*4, stream);
  hist_k<<<ebk, THREADS, 0, stream>>>(ei, cnt, rank, Ee, ET);
  scan1_k<<<NB, 1024, 0, stream>>>(cnt, off, bsum, Nn);
  scan2_k<<<1, 256, 0, stream>>>(bsum, NB);
  scan3_k<<<NB, 1024, 0, stream>>>(off, bsum, Nn);
  scatter_k<<<ebk, THREADS, 0, stream>>>(ei, off, rank, csr, Ee, ET);

  // dtype prep + fused-alpha B-columns + graph boundaries
  convf2b_k<<<(Nn*32 + THREADS-1)/THREADS, THREADS, 0, stream>>>((const float4*)x, (uint2*)bufA, Nn*32);
  wt_k<<<(128*192 + THREADS-1)/THREADS, THREADS, 0, stream>>>(W1, WT1, 128, 192);
  wt_k<<<(192*96  + THREADS-1)/THREADS, THREADS, 0, stream>>>(W2, WT2, 192, 96);
  wt_k<<<(96*48   + THREADS-1)/THREADS, THREADS, 0, stream>>>(W3, WT3, 96, 48);
  va_k<<<(6*128 + THREADS-1)/THREADS, THREADS, 0, stream>>>(W1, as1, ad1, WT1, 128, 64, 192);
  va_k<<<(6*192 + THREADS-1)/THREADS, THREADS, 0, stream>>>(W2, as2, ad2, WT2, 192, 32, 96);
  va_k<<<(6*96  + THREADS-1)/THREADS, THREADS, 0, stream>>>(W3, as3, ad3, WT3, 96, 16, 48);
  gboff_k<<<(Gg + 1 + THREADS-1)/THREADS, THREADS, 0, stream>>>(batch, goff, Nn, Gg);

  int nRT = Nn / 16;                 // 6250 row tiles
  int gx  = (nRT + 3) / 4;           // 4 waves/block
  int gb1 = (Nn + 3) / 4;            // GRP=64: 1 node/wave
  int gb2 = (Nn + 7) / 8;            // GRP=32: 2 nodes/wave
  int gb3 = (Nn + 15) / 16;          // GRP=16: 4 nodes/wave

  // layer 1: 128 -> 3x64
  gemm_mfma_k<128,192><<<gx, 256, 0, stream>>>(bufA, WT1, bufH, aS4, aD4, nRT);
  wgtden_k<<<nbk, THREADS, 0, stream>>>(off, csr, aS4, aD4, wbuf, den4, Nn);
  agg_k<192,6,64><<<gb1, 256, 0, stream>>>(off, csr, bufH, wbuf, den4, b1, nullptr, bufA, Nn, 1);
  // layer 2: 192 -> 3x32
  gemm_mfma_k<192,96><<<gx, 256, 0, stream>>>(bufA, WT2, bufH, aS4, aD4, nRT);
  wgtden_k<<<nbk, THREADS, 0, stream>>>(off, csr, aS4, aD4, wbuf, den4, Nn);
  agg_k<96,5,32><<<gb2, 256, 0, stream>>>(off, csr, bufH, wbuf, den4, b2, nullptr, bufA, Nn, 1);
  // layer 3: 96 -> 3x16 (no ELU)
  gemm_mfma_k<96,48><<<gx, 256, 0, stream>>>(bufA, WT3, bufH, aS4, aD4, nRT);
  wgtden_k<<<nbk, THREADS, 0, stream>>>(off, csr, aS4, aD4, wbuf, den4, Nn);
  agg_k<48,4,16><<<gb3, 256, 0, stream>>>(off, csr, bufH, wbuf, den4, b3, bufO, nullptr, Nn, 0);

  // fused mean pool + relu + linear + sigmoid + BCE loss
  hipMemsetAsync(lossAcc, 0, 4, stream);
  pool_logits_k<<<(Gg + 3)/4, 256, 0, stream>>>(bufO, goff, Wl, bl, y, outp, lossAcc, Gg);
  fin_k<<<1, 1, 0, stream>>>(lossAcc, outp, Gg);
}

// Round 12
// 651.927 us; speedup vs baseline: 2.4612x; 1.1063x over previous
//
#include <hip/hip_runtime.h>
#include <hip/hip_bf16.h>

#define THREADS 256
typedef __hip_bfloat16 bf16;

typedef __bf16 v8bf __attribute__((ext_vector_type(8)));
typedef float  v4f  __attribute__((ext_vector_type(4)));

__device__ __forceinline__ float bfl(unsigned u){ return __uint_as_float(u << 16); }
__device__ __forceinline__ float bfh(unsigned u){ return __uint_as_float(u & 0xffff0000u); }

// ---------------- CSR build (group edges by destination) ----------------
// hist also records each edge's rank within its destination bucket -> scatter needs no atomics.
__global__ void hist_k(const int* __restrict__ ei, int* __restrict__ cnt,
                       int* __restrict__ rank, int E, int ET){
  int i = blockIdx.x*THREADS + threadIdx.x;
  if (i >= ET) return;
  int d = (i < E) ? ei[E + i] : (i - E);   // self-loops appended
  rank[i] = atomicAdd(&cnt[d], 1);
}

__global__ void scan1_k(const int* __restrict__ deg, int* __restrict__ off,
                        int* __restrict__ bsum, int n){
  __shared__ int sh[1024];
  int i = blockIdx.x*1024 + threadIdx.x;
  int v = (i < n) ? deg[i] : 0;
  sh[threadIdx.x] = v;
  __syncthreads();
  for (int s = 1; s < 1024; s <<= 1){
    int t = (threadIdx.x >= s) ? sh[threadIdx.x - s] : 0;
    __syncthreads();
    sh[threadIdx.x] += t;
    __syncthreads();
  }
  if (i < n) off[i+1] = sh[threadIdx.x];
  if (threadIdx.x == 1023) bsum[blockIdx.x] = sh[1023];
}

__global__ void scan2_k(int* __restrict__ bsum, int nb){
  __shared__ int sh[256];
  int v = (threadIdx.x < nb) ? bsum[threadIdx.x] : 0;
  sh[threadIdx.x] = v;
  __syncthreads();
  for (int s = 1; s < 256; s <<= 1){
    int t = (threadIdx.x >= s) ? sh[threadIdx.x - s] : 0;
    __syncthreads();
    sh[threadIdx.x] += t;
    __syncthreads();
  }
  if (threadIdx.x < nb) bsum[threadIdx.x] = sh[threadIdx.x] - v;  // exclusive
}

__global__ void scan3_k(int* __restrict__ off, const int* __restrict__ bsum, int n){
  int i = blockIdx.x*1024 + threadIdx.x;
  if (i < n) off[i+1] += bsum[blockIdx.x];
  if (i == 0) off[0] = 0;
}

__global__ void scatter_k(const int* __restrict__ ei, const int* __restrict__ off,
                          const int* __restrict__ rank, int* __restrict__ csr,
                          int E, int ET){
  int i = blockIdx.x*THREADS + threadIdx.x;
  if (i >= ET) return;
  int s, d;
  if (i < E){ s = ei[i]; d = ei[E+i]; } else { s = i - E; d = i - E; }
  csr[off[d] + rank[i]] = s;
}

// ---------------- dtype prep ----------------
__global__ void convf2b_k(const float4* __restrict__ in, uint2* __restrict__ out, int n4){
  int i = blockIdx.x*THREADS + threadIdx.x;
  if (i >= n4) return;
  float4 v = in[i];
  union { bf16 h[4]; uint2 u; } cv;
  cv.h[0] = __float2bfloat16(v.x); cv.h[1] = __float2bfloat16(v.y);
  cv.h[2] = __float2bfloat16(v.z); cv.h[3] = __float2bfloat16(v.w);
  out[i] = cv.u;
}

// WT[c*K + k] = bf16(W[k*COUT + c])
__global__ void wt_k(const float* __restrict__ W, bf16* __restrict__ WT, int K, int COUT){
  int i = blockIdx.x*THREADS + threadIdx.x;
  if (i >= K*COUT) return;
  int k = i / COUT, c = i - k*COUT;
  WT[(size_t)c*K + k] = __float2bfloat16(W[i]);
}

// extra B-columns for fused alpha: WTX rows COUT..COUT+2 = W_h @ as_h, COUT+3..+5 = W_h @ ad_h
__global__ void va_k(const float* __restrict__ W, const float* __restrict__ as,
                     const float* __restrict__ ad, bf16* __restrict__ WTX,
                     int K, int C, int COUT){
  int i = blockIdx.x*THREADS + threadIdx.x;
  if (i >= 6*K) return;
  int k = i % K, c6 = i / K;
  int h = (c6 < 3) ? c6 : c6 - 3;
  const float* a = ((c6 < 3) ? as : ad) + h*C;
  const float* wp = W + (size_t)k*COUT + h*C;
  float s = 0.f;
  for (int cc = 0; cc < C; cc++) s += wp[cc]*a[cc];
  WTX[(size_t)(COUT + c6)*K + k] = __float2bfloat16(s);
}

// ---------------- MFMA GEMM fused with alpha: C = A@B, aS/aD from extra tile ----
template<int K, int COUT>
__global__ void __launch_bounds__(256) gemm_mfma_k(
    const bf16* __restrict__ A, const bf16* __restrict__ BT,
    bf16* __restrict__ C, float* __restrict__ aS4, float* __restrict__ aD4,
    int nRowTiles)
{
  int wave = threadIdx.x >> 6, lane = threadIdx.x & 63;
  int rt = blockIdx.x*4 + wave;
  if (rt >= nRowTiles) return;
  int half = lane & 15;
  int quad = lane >> 4;
  const __bf16* aBase = (const __bf16*)A + (size_t)(rt*16 + half)*K + quad*8;
  v8bf aF[K/32];
  #pragma unroll
  for (int kk = 0; kk < K/32; kk++) aF[kk] = *(const v8bf*)(aBase + kk*32);
  #pragma unroll
  for (int cb = 0; cb < COUT + 16; cb += 16){
    const __bf16* bBase = (const __bf16*)BT + (size_t)(cb + half)*K + quad*8;
    v4f acc = {0.f, 0.f, 0.f, 0.f};
    #pragma unroll
    for (int kk = 0; kk < K/32; kk++)
      acc = __builtin_amdgcn_mfma_f32_16x16x32_bf16(aF[kk], *(const v8bf*)(bBase + kk*32), acc, 0, 0, 0);
    int orow = rt*16 + quad*4;                 // D: col=lane&15, row=quad*4+reg
    if (cb < COUT){
      bf16* cp = C + (size_t)orow*COUT + cb + half;
      #pragma unroll
      for (int r = 0; r < 4; r++)
        cp[(size_t)r*COUT] = __float2bfloat16(acc[r]);
    } else if (half < 6){
      #pragma unroll
      for (int r = 0; r < 4; r++){
        int row = orow + r;
        if (half < 3) aS4[row*4 + half]     = acc[r];
        else          aD4[row*4 + half - 3] = acc[r];
      }
    }
  }
}

// ---------------- fused softmax-weight + aggregation (GRP lanes per dst node) -------
// Per chunk of GRP edges: phase A, lane q computes edge (base+q)'s 3 exp-weights + src
// into its wave's LDS slot (16 B); wave-internal fence; phase B, active lanes stream the
// chunk via broadcast ds_read_b128, accumulating own-head denominator and weighted h.
template<int HC, int CSH, int GRP>
__global__ void __launch_bounds__(256) agg_k(
    const int* __restrict__ off, const int* __restrict__ csr,
    const bf16* __restrict__ hbuf,
    const float* __restrict__ aS4, const float* __restrict__ aD4,
    const float* __restrict__ bias,
    float* __restrict__ outF, bf16* __restrict__ outB,
    int n, int doElu)
{
  constexpr int NPW = 64 / GRP;
  __shared__ float wls[4][256];              // [wave][lane*4 + {w0,w1,w2,srcbits}]
  int tid = threadIdx.x;
  int wave = tid >> 6;
  int lane = tid & 63;
  int q = lane % GRP;
  int grp = lane / GRP;
  int wv = (blockIdx.x*256 + tid) >> 6;
  int node = wv*NPW + grp;
  bool valid = node < n;
  int e0 = 0, e1 = 0;
  float4 ad = {0.f, 0.f, 0.f, 0.f};
  if (valid){
    e0 = off[node]; e1 = off[node+1];
    ad = *(const float4*)(aD4 + 4*node);
  }
  const int hq = (4*q) >> CSH;               // head of this lane's 4 channels
  const bool act = valid && (q < HC/4);
  const size_t hoff = 4*q;
  float dh = 0.f;
  float a0 = 0.f, a1 = 0.f, a2 = 0.f, a3 = 0.f;
  float* myw = &wls[wave][grp*GRP*4];

  int nch = (e1 - e0 + GRP - 1) / GRP;
  for (int c = 0; c < nch; c++){
    int base = e0 + c*GRP;
    __threadfence_block();                   // WAR: prior chunk's reads drained
    int j = base + q;
    if (j < e1){
      int s = csr[j];
      float4 av = *(const float4*)(aS4 + 4*s);
      float x0 = av.x + ad.x; x0 = (x0 > 0.f) ? x0 : 0.2f*x0;
      float x1 = av.y + ad.y; x1 = (x1 > 0.f) ? x1 : 0.2f*x1;
      float x2 = av.z + ad.z; x2 = (x2 > 0.f) ? x2 : 0.2f*x2;
      float4 st = {__expf(x0), __expf(x1), __expf(x2), __int_as_float(s)};
      *(float4*)(myw + q*4) = st;
    }
    __threadfence_block();                   // writes visible within wave
    if (act){
      int lim = e1 - base; if (lim > GRP) lim = GRP;
      int jj = 0;
      for (; jj + 4 <= lim; jj += 4){
        float4 wA = *(const float4*)(myw + (jj+0)*4);
        float4 wB = *(const float4*)(myw + (jj+1)*4);
        float4 wC = *(const float4*)(myw + (jj+2)*4);
        float4 wD = *(const float4*)(myw + (jj+3)*4);
        int s0 = __float_as_int(wA.w), s1 = __float_as_int(wB.w);
        int s2 = __float_as_int(wC.w), s3 = __float_as_int(wD.w);
        float w0 = (hq == 0) ? wA.x : ((hq == 1) ? wA.y : wA.z);
        float w1 = (hq == 0) ? wB.x : ((hq == 1) ? wB.y : wB.z);
        float w2 = (hq == 0) ? wC.x : ((hq == 1) ? wC.y : wC.z);
        float w3 = (hq == 0) ? wD.x : ((hq == 1) ? wD.y : wD.z);
        uint2 u0 = *(const uint2*)(hbuf + (size_t)s0*HC + hoff);
        uint2 u1 = *(const uint2*)(hbuf + (size_t)s1*HC + hoff);
        uint2 u2 = *(const uint2*)(hbuf + (size_t)s2*HC + hoff);
        uint2 u3 = *(const uint2*)(hbuf + (size_t)s3*HC + hoff);
        dh += w0 + w1 + w2 + w3;
        a0 += w0*bfl(u0.x); a1 += w0*bfh(u0.x); a2 += w0*bfl(u0.y); a3 += w0*bfh(u0.y);
        a0 += w1*bfl(u1.x); a1 += w1*bfh(u1.x); a2 += w1*bfl(u1.y); a3 += w1*bfh(u1.y);
        a0 += w2*bfl(u2.x); a1 += w2*bfh(u2.x); a2 += w2*bfl(u2.y); a3 += w2*bfh(u2.y);
        a0 += w3*bfl(u3.x); a1 += w3*bfh(u3.x); a2 += w3*bfl(u3.y); a3 += w3*bfh(u3.y);
      }
      for (; jj < lim; jj++){
        float4 wA = *(const float4*)(myw + jj*4);
        int s = __float_as_int(wA.w);
        float w = (hq == 0) ? wA.x : ((hq == 1) ? wA.y : wA.z);
        uint2 u = *(const uint2*)(hbuf + (size_t)s*HC + hoff);
        dh += w;
        a0 += w*bfl(u.x); a1 += w*bfh(u.x); a2 += w*bfl(u.y); a3 += w*bfh(u.y);
      }
    }
  }
  if (act){
    float inv = 1.f / (dh + 1e-16f);
    const float4 b = *(const float4*)(bias + 4*q);
    float r0 = a0*inv + b.x, r1 = a1*inv + b.y, r2 = a2*inv + b.z, r3 = a3*inv + b.w;
    if (doElu){
      r0 = (r0 > 0.f) ? r0 : (__expf(r0) - 1.f);
      r1 = (r1 > 0.f) ? r1 : (__expf(r1) - 1.f);
      r2 = (r2 > 0.f) ? r2 : (__expf(r2) - 1.f);
      r3 = (r3 > 0.f) ? r3 : (__expf(r3) - 1.f);
    }
    if (outF){
      float4 o = {r0, r1, r2, r3};
      *(float4*)(outF + (size_t)node*HC + 4*q) = o;
    }
    if (outB){
      union { bf16 h[4]; uint2 u; } cv;
      cv.h[0] = __float2bfloat16(r0); cv.h[1] = __float2bfloat16(r1);
      cv.h[2] = __float2bfloat16(r2); cv.h[3] = __float2bfloat16(r3);
      *(uint2*)(outB + (size_t)node*HC + 4*q) = cv.u;
    }
  }
}

// ---------------- graph boundaries via binary search on sorted batch ----------------
__global__ void gboff_k(const int* __restrict__ batch, int* __restrict__ goff, int n, int G){
  int g = blockIdx.x*THREADS + threadIdx.x;
  if (g > G) return;
  if (g == G){ goff[G] = n; return; }
  int lo = 0, hi = n;
  while (lo < hi){ int mid = (lo + hi) >> 1; if (batch[mid] < g) lo = mid + 1; else hi = mid; }
  goff[g] = lo;
}

// ---------------- fused mean-pool + relu + linear + sigmoid + BCE (wave per graph) ---
__global__ void __launch_bounds__(256) pool_logits_k(
    const float* __restrict__ h3, const int* __restrict__ goff,
    const float* __restrict__ Wl, const float* __restrict__ bl,
    const float* __restrict__ y, float* __restrict__ outp,
    float* __restrict__ lossAcc, int G)
{
  int lane = threadIdx.x & 63;
  int g = (blockIdx.x*256 + threadIdx.x) >> 6;
  if (g >= G) return;
  int n0 = goff[g], n1 = goff[g+1];
  int cnt = n1 - n0;
  float acc = 0.f, acc2 = 0.f, wl = 0.f;
  if (lane < 48){
    wl = Wl[lane];
    const float* p = h3 + (size_t)n0*48 + lane;
    int i = 0;
    for (; i + 2 <= cnt; i += 2){ acc += p[(size_t)i*48]; acc2 += p[(size_t)(i+1)*48]; }
    if (i < cnt) acc += p[(size_t)i*48];
    acc += acc2;
  }
  float inv = 1.f / fmaxf((float)cnt, 1.f);
  float v = fmaxf(acc*inv, 0.f) * wl;
  for (int o = 32; o > 0; o >>= 1) v += __shfl_down(v, o);
  if (lane == 0){
    float logit = v + bl[0];
    outp[g] = 1.f / (1.f + __expf(-logit));
    float t = y[g];
    float sp = (logit > 0.f) ? (logit + log1pf(__expf(-logit))) : log1pf(__expf(logit));
    atomicAdd(lossAcc, sp - t*logit);
  }
}

__global__ void fin_k(const float* __restrict__ lossAcc, float* __restrict__ outp, int gtot){
  outp[gtot] = lossAcc[0] / (float)gtot;
}

// ---------------- launch ----------------
extern "C" void kernel_launch(void* const* d_in, const int* in_sizes, int n_in,
                              void* d_out, int out_size, void* d_ws, size_t ws_size,
                              hipStream_t stream)
{
  (void)n_in; (void)out_size; (void)ws_size;
  const float* x    = (const float*)d_in[0];
  const float* y    = (const float*)d_in[1];
  const int*  ei    = (const int*)d_in[2];
  const int*  batch = (const int*)d_in[3];
  const float* W1 = (const float*)d_in[4];
  const float* as1= (const float*)d_in[5];
  const float* ad1= (const float*)d_in[6];
  const float* b1 = (const float*)d_in[7];
  const float* W2 = (const float*)d_in[8];
  const float* as2= (const float*)d_in[9];
  const float* ad2= (const float*)d_in[10];
  const float* b2 = (const float*)d_in[11];
  const float* W3 = (const float*)d_in[12];
  const float* as3= (const float*)d_in[13];
  const float* ad3= (const float*)d_in[14];
  const float* b3 = (const float*)d_in[15];
  const float* Wl = (const float*)d_in[16];
  const float* bl = (const float*)d_in[17];
  float* outp = (float*)d_out;

  int Nn = in_sizes[0] / 128;   // 100000 (multiple of 16)
  int Gg = in_sizes[1];
  int Ee = in_sizes[2] / 2;
  int ET = Ee + Nn;

  char* p = (char*)d_ws;
  auto carve = [&](size_t bytes) -> void* {
    void* r = (void*)p; p += (bytes + 255) & ~(size_t)255; return r;
  };
  int*   off     = (int*)  carve((size_t)(Nn+1)*4);
  int*   cnt     = (int*)  carve((size_t)Nn*4);
  int*   csr     = (int*)  carve((size_t)ET*4);
  int*   rank    = (int*)  carve((size_t)ET*4);
  int*   bsum    = (int*)  carve(256*4);
  float* aS4     = (float*)carve((size_t)Nn*4*4);
  float* aD4     = (float*)carve((size_t)Nn*4*4);
  int*   goff    = (int*)  carve((size_t)(Gg+1)*4);
  float* lossAcc = (float*)carve(4);
  bf16*  WT1     = (bf16*) carve((size_t)(192+16)*128*2);
  bf16*  WT2     = (bf16*) carve((size_t)(96+16)*192*2);
  bf16*  WT3     = (bf16*) carve((size_t)(48+16)*96*2);
  bf16*  bufH    = (bf16*) carve((size_t)Nn*192*2);   // GEMM out (h), agg in
  bf16*  bufA    = (bf16*) carve((size_t)Nn*192*2);   // GEMM A-operand
  // layer-3 f32 out for pooling: alias into the unused tail of bufH's region
  float* bufO    = (float*)((char*)bufH + ((size_t)Nn*96 + 255 & ~(size_t)255));

  int NB = (Nn + 1023) / 1024;
  int ebk = (ET + THREADS - 1) / THREADS;

  // CSR by destination (atomic-free scatter via rank)
  hipMemsetAsync(cnt, 0, (size_t)Nn*4, stream);
  hist_k<<<ebk, THREADS, 0, stream>>>(ei, cnt, rank, Ee, ET);
  scan1_k<<<NB, 1024, 0, stream>>>(cnt, off, bsum, Nn);
  scan2_k<<<1, 256, 0, stream>>>(bsum, NB);
  scan3_k<<<NB, 1024, 0, stream>>>(off, bsum, Nn);
  scatter_k<<<ebk, THREADS, 0, stream>>>(ei, off, rank, csr, Ee, ET);

  // dtype prep + fused-alpha B-columns + graph boundaries
  convf2b_k<<<(Nn*32 + THREADS-1)/THREADS, THREADS, 0, stream>>>((const float4*)x, (uint2*)bufA, Nn*32);
  wt_k<<<(128*192 + THREADS-1)/THREADS, THREADS, 0, stream>>>(W1, WT1, 128, 192);
  wt_k<<<(192*96  + THREADS-1)/THREADS, THREADS, 0, stream>>>(W2, WT2, 192, 96);
  wt_k<<<(96*48   + THREADS-1)/THREADS, THREADS, 0, stream>>>(W3, WT3, 96, 48);
  va_k<<<(6*128 + THREADS-1)/THREADS, THREADS, 0, stream>>>(W1, as1, ad1, WT1, 128, 64, 192);
  va_k<<<(6*192 + THREADS-1)/THREADS, THREADS, 0, stream>>>(W2, as2, ad2, WT2, 192, 32, 96);
  va_k<<<(6*96  + THREADS-1)/THREADS, THREADS, 0, stream>>>(W3, as3, ad3, WT3, 96, 16, 48);
  gboff_k<<<(Gg + 1 + THREADS-1)/THREADS, THREADS, 0, stream>>>(batch, goff, Nn, Gg);

  int nRT = Nn / 16;                 // 6250 row tiles
  int gx  = (nRT + 3) / 4;           // 4 waves/block
  int gb1 = (Nn + 3) / 4;            // GRP=64: 1 node/wave
  int gb2 = (Nn + 7) / 8;            // GRP=32: 2 nodes/wave
  int gb3 = (Nn + 15) / 16;          // GRP=16: 4 nodes/wave

  // layer 1: 128 -> 3x64
  gemm_mfma_k<128,192><<<gx, 256, 0, stream>>>(bufA, WT1, bufH, aS4, aD4, nRT);
  agg_k<192,6,64><<<gb1, 256, 0, stream>>>(off, csr, bufH, aS4, aD4, b1, nullptr, bufA, Nn, 1);
  // layer 2: 192 -> 3x32
  gemm_mfma_k<192,96><<<gx, 256, 0, stream>>>(bufA, WT2, bufH, aS4, aD4, nRT);
  agg_k<96,5,32><<<gb2, 256, 0, stream>>>(off, csr, bufH, aS4, aD4, b2, nullptr, bufA, Nn, 1);
  // layer 3: 96 -> 3x16 (no ELU)
  gemm_mfma_k<96,48><<<gx, 256, 0, stream>>>(bufA, WT3, bufH, aS4, aD4, nRT);
  agg_k<48,4,16><<<gb3, 256, 0, stream>>>(off, csr, bufH, aS4, aD4, b3, bufO, nullptr, Nn, 0);

  // fused mean pool + relu + linear + sigmoid + BCE loss
  hipMemsetAsync(lossAcc, 0, 4, stream);
  pool_logits_k<<<(Gg + 3)/4, 256, 0, stream>>>(bufO, goff, Wl, bl, y, outp, lossAcc, Gg);
  fin_k<<<1, 1, 0, stream>>>(lossAcc, outp, Gg);
}

// Round 13
// 625.434 us; speedup vs baseline: 2.5655x; 1.0424x over previous
//
#include <hip/hip_runtime.h>
#include <hip/hip_bf16.h>

#define THREADS 256
typedef __hip_bfloat16 bf16;

typedef __bf16 v8bf __attribute__((ext_vector_type(8)));
typedef float  v4f  __attribute__((ext_vector_type(4)));

__device__ __forceinline__ float bfl(unsigned u){ return __uint_as_float(u << 16); }
__device__ __forceinline__ float bfh(unsigned u){ return __uint_as_float(u & 0xffff0000u); }

// ---------------- CSR build (group edges by destination) ----------------
__global__ void hist_k(const int* __restrict__ ei, int* __restrict__ cnt,
                       int* __restrict__ rank, int E, int ET){
  int i = blockIdx.x*THREADS + threadIdx.x;
  if (i >= ET) return;
  int d = (i < E) ? ei[E + i] : (i - E);   // self-loops appended
  rank[i] = atomicAdd(&cnt[d], 1);
}

__global__ void scan1_k(const int* __restrict__ deg, int* __restrict__ off,
                        int* __restrict__ bsum, int n){
  __shared__ int sh[1024];
  int i = blockIdx.x*1024 + threadIdx.x;
  int v = (i < n) ? deg[i] : 0;
  sh[threadIdx.x] = v;
  __syncthreads();
  for (int s = 1; s < 1024; s <<= 1){
    int t = (threadIdx.x >= s) ? sh[threadIdx.x - s] : 0;
    __syncthreads();
    sh[threadIdx.x] += t;
    __syncthreads();
  }
  if (i < n) off[i+1] = sh[threadIdx.x];
  if (threadIdx.x == 1023) bsum[blockIdx.x] = sh[1023];
}

__global__ void scan2_k(int* __restrict__ bsum, int nb){
  __shared__ int sh[256];
  int v = (threadIdx.x < nb) ? bsum[threadIdx.x] : 0;
  sh[threadIdx.x] = v;
  __syncthreads();
  for (int s = 1; s < 256; s <<= 1){
    int t = (threadIdx.x >= s) ? sh[threadIdx.x - s] : 0;
    __syncthreads();
    sh[threadIdx.x] += t;
    __syncthreads();
  }
  if (threadIdx.x < nb) bsum[threadIdx.x] = sh[threadIdx.x] - v;  // exclusive
}

__global__ void scan3_k(int* __restrict__ off, const int* __restrict__ bsum, int n){
  int i = blockIdx.x*1024 + threadIdx.x;
  if (i < n) off[i+1] += bsum[blockIdx.x];
  if (i == 0) off[0] = 0;
}

__global__ void scatter_k(const int* __restrict__ ei, const int* __restrict__ off,
                          const int* __restrict__ rank, int* __restrict__ csr,
                          int E, int ET){
  int i = blockIdx.x*THREADS + threadIdx.x;
  if (i >= ET) return;
  int s, d;
  if (i < E){ s = ei[i]; d = ei[E+i]; } else { s = i - E; d = i - E; }
  csr[off[d] + rank[i]] = s;
}

// ---------------- dtype prep ----------------
__global__ void convf2b_k(const float4* __restrict__ in, uint2* __restrict__ out, int n4){
  int i = blockIdx.x*THREADS + threadIdx.x;
  if (i >= n4) return;
  float4 v = in[i];
  union { bf16 h[4]; uint2 u; } cv;
  cv.h[0] = __float2bfloat16(v.x); cv.h[1] = __float2bfloat16(v.y);
  cv.h[2] = __float2bfloat16(v.z); cv.h[3] = __float2bfloat16(v.w);
  out[i] = cv.u;
}

__device__ __forceinline__ void wt_do(const float* __restrict__ W, bf16* __restrict__ WT,
                                      int K, int COUT, int i){
  int k = i / COUT, c = i - k*COUT;
  WT[(size_t)c*K + k] = __float2bfloat16(W[i]);
}

__device__ __forceinline__ void va_do(const float* __restrict__ W, const float* __restrict__ as,
                                      const float* __restrict__ ad, bf16* __restrict__ WTX,
                                      int K, int C, int COUT, int i){
  int k = i % K, c6 = i / K;
  int h = (c6 < 3) ? c6 : c6 - 3;
  const float* a = ((c6 < 3) ? as : ad) + h*C;
  const float* wp = W + (size_t)k*COUT + h*C;
  float s = 0.f;
  for (int cc = 0; cc < C; cc++) s += wp[cc]*a[cc];
  WTX[(size_t)(COUT + c6)*K + k] = __float2bfloat16(s);
}

// one launch: all W transposes + fused-alpha extra columns + graph boundaries
__global__ void prep_k(const float* __restrict__ W1, const float* __restrict__ as1, const float* __restrict__ ad1,
                       const float* __restrict__ W2, const float* __restrict__ as2, const float* __restrict__ ad2,
                       const float* __restrict__ W3, const float* __restrict__ as3, const float* __restrict__ ad3,
                       bf16* __restrict__ WT1, bf16* __restrict__ WT2, bf16* __restrict__ WT3,
                       const int* __restrict__ batch, int* __restrict__ goff, int n, int G)
{
  int i = blockIdx.x*THREADS + threadIdx.x;
  if (i < 24576){ wt_do(W1, WT1, 128, 192, i); return; } i -= 24576;
  if (i < 18432){ wt_do(W2, WT2, 192, 96, i); return; }  i -= 18432;
  if (i < 4608) { wt_do(W3, WT3, 96, 48, i); return; }   i -= 4608;
  if (i < 768)  { va_do(W1, as1, ad1, WT1, 128, 64, 192, i); return; } i -= 768;
  if (i < 1152) { va_do(W2, as2, ad2, WT2, 192, 32, 96, i); return; }  i -= 1152;
  if (i < 576)  { va_do(W3, as3, ad3, WT3, 96, 16, 48, i); return; }   i -= 576;
  if (i <= G){
    if (i == G){ goff[G] = n; return; }
    int lo = 0, hi = n;
    while (lo < hi){ int mid = (lo + hi) >> 1; if (batch[mid] < i) lo = mid + 1; else hi = mid; }
    goff[i] = lo;
  }
}

// ---------------- MFMA GEMM fused with alpha: C = A@B, aS/aD from extra tile ----
template<int K, int COUT>
__global__ void __launch_bounds__(256) gemm_mfma_k(
    const bf16* __restrict__ A, const bf16* __restrict__ BT,
    bf16* __restrict__ C, float* __restrict__ aS4, float* __restrict__ aD4,
    int nRowTiles)
{
  int wave = threadIdx.x >> 6, lane = threadIdx.x & 63;
  int rt = blockIdx.x*4 + wave;
  if (rt >= nRowTiles) return;
  int half = lane & 15;
  int quad = lane >> 4;
  const __bf16* aBase = (const __bf16*)A + (size_t)(rt*16 + half)*K + quad*8;
  v8bf aF[K/32];
  #pragma unroll
  for (int kk = 0; kk < K/32; kk++) aF[kk] = *(const v8bf*)(aBase + kk*32);
  #pragma unroll
  for (int cb = 0; cb < COUT + 16; cb += 16){
    const __bf16* bBase = (const __bf16*)BT + (size_t)(cb + half)*K + quad*8;
    v4f acc = {0.f, 0.f, 0.f, 0.f};
    #pragma unroll
    for (int kk = 0; kk < K/32; kk++)
      acc = __builtin_amdgcn_mfma_f32_16x16x32_bf16(aF[kk], *(const v8bf*)(bBase + kk*32), acc, 0, 0, 0);
    int orow = rt*16 + quad*4;                 // D: col=lane&15, row=quad*4+reg
    if (cb < COUT){
      bf16* cp = C + (size_t)orow*COUT + cb + half;
      #pragma unroll
      for (int r = 0; r < 4; r++)
        cp[(size_t)r*COUT] = __float2bfloat16(acc[r]);
    } else if (half < 6){
      #pragma unroll
      for (int r = 0; r < 4; r++){
        int row = orow + r;
        if (half < 3) aS4[row*4 + half]     = acc[r];
        else          aD4[row*4 + half - 3] = acc[r];
      }
    }
  }
}

// ---------------- fused softmax-weight + aggregation (GRP lanes per dst node) -------
// Phase A: lane q computes edge (base+q)'s 3 exp-weights, stores {w_h, src} per head
// (3 x ds_write_b64). Phase B: active lanes stream their OWN head's array — one
// broadcast ds_read_b128 covers TWO edges; no per-edge head select.
template<int HC, int CSH, int GRP>
__global__ void __launch_bounds__(256) agg_k(
    const int* __restrict__ off, const int* __restrict__ csr,
    const bf16* __restrict__ hbuf,
    const float* __restrict__ aS4, const float* __restrict__ aD4,
    const float* __restrict__ bias,
    float* __restrict__ outF, bf16* __restrict__ outB,
    int n, int doElu)
{
  constexpr int NPW = 64 / GRP;
  __shared__ __align__(16) float wls[4][384];   // per wave: NPW groups x 3 heads x GRP float2
  int tid = threadIdx.x;
  int wave = tid >> 6;
  int lane = tid & 63;
  int q = lane % GRP;
  int grp = lane / GRP;
  int wv = (blockIdx.x*256 + tid) >> 6;
  int node = wv*NPW + grp;
  bool valid = node < n;
  int e0 = 0, e1 = 0;
  float4 ad = {0.f, 0.f, 0.f, 0.f};
  if (valid){
    e0 = off[node]; e1 = off[node+1];
    ad = *(const float4*)(aD4 + 4*node);
  }
  const int hq = (4*q) >> CSH;               // head of this lane's 4 channels
  const bool act = valid && (q < HC/4);
  const size_t hoff = 4*q;
  float dh = 0.f;
  float a0 = 0.f, a1 = 0.f, a2 = 0.f, a3 = 0.f;
  float* gbase = &wls[wave][grp*3*GRP*2];    // this group's region
  const float* wh = gbase + hq*GRP*2;        // own-head stream (phase B)

  int nch = (e1 - e0 + GRP - 1) / GRP;
  for (int c = 0; c < nch; c++){
    int base = e0 + c*GRP;
    __threadfence_block();                   // WAR: prior chunk's reads drained
    int j = base + q;
    if (j < e1){
      int s = csr[j];
      float4 av = *(const float4*)(aS4 + 4*s);
      float x0 = av.x + ad.x; x0 = (x0 > 0.f) ? x0 : 0.2f*x0;
      float x1 = av.y + ad.y; x1 = (x1 > 0.f) ? x1 : 0.2f*x1;
      float x2 = av.z + ad.z; x2 = (x2 > 0.f) ? x2 : 0.2f*x2;
      float sf = __int_as_float(s);
      float2 p0 = {__expf(x0), sf};
      float2 p1 = {__expf(x1), sf};
      float2 p2 = {__expf(x2), sf};
      *(float2*)(gbase + (0*GRP + q)*2) = p0;
      *(float2*)(gbase + (1*GRP + q)*2) = p1;
      *(float2*)(gbase + (2*GRP + q)*2) = p2;
    }
    __threadfence_block();                   // writes visible within wave
    if (act){
      int lim = e1 - base; if (lim > GRP) lim = GRP;
      int jj = 0;
      for (; jj + 4 <= lim; jj += 4){
        float4 pA = *(const float4*)(wh + jj*2);       // edges jj, jj+1
        float4 pB = *(const float4*)(wh + jj*2 + 4);   // edges jj+2, jj+3
        int s0 = __float_as_int(pA.y), s1 = __float_as_int(pA.w);
        int s2 = __float_as_int(pB.y), s3 = __float_as_int(pB.w);
        float w0 = pA.x, w1 = pA.z, w2 = pB.x, w3 = pB.z;
        uint2 u0 = *(const uint2*)(hbuf + (size_t)s0*HC + hoff);
        uint2 u1 = *(const uint2*)(hbuf + (size_t)s1*HC + hoff);
        uint2 u2 = *(const uint2*)(hbuf + (size_t)s2*HC + hoff);
        uint2 u3 = *(const uint2*)(hbuf + (size_t)s3*HC + hoff);
        dh += w0 + w1 + w2 + w3;
        a0 += w0*bfl(u0.x); a1 += w0*bfh(u0.x); a2 += w0*bfl(u0.y); a3 += w0*bfh(u0.y);
        a0 += w1*bfl(u1.x); a1 += w1*bfh(u1.x); a2 += w1*bfl(u1.y); a3 += w1*bfh(u1.y);
        a0 += w2*bfl(u2.x); a1 += w2*bfh(u2.x); a2 += w2*bfl(u2.y); a3 += w2*bfh(u2.y);
        a0 += w3*bfl(u3.x); a1 += w3*bfh(u3.x); a2 += w3*bfl(u3.y); a3 += w3*bfh(u3.y);
      }
      for (; jj < lim; jj++){
        float2 pw = *(const float2*)(wh + jj*2);
        int s = __float_as_int(pw.y);
        float w = pw.x;
        uint2 u = *(const uint2*)(hbuf + (size_t)s*HC + hoff);
        dh += w;
        a0 += w*bfl(u.x); a1 += w*bfh(u.x); a2 += w*bfl(u.y); a3 += w*bfh(u.y);
      }
    }
  }
  if (act){
    float inv = 1.f / (dh + 1e-16f);
    const float4 b = *(const float4*)(bias + 4*q);
    float r0 = a0*inv + b.x, r1 = a1*inv + b.y, r2 = a2*inv + b.z, r3 = a3*inv + b.w;
    if (doElu){
      r0 = (r0 > 0.f) ? r0 : (__expf(r0) - 1.f);
      r1 = (r1 > 0.f) ? r1 : (__expf(r1) - 1.f);
      r2 = (r2 > 0.f) ? r2 : (__expf(r2) - 1.f);
      r3 = (r3 > 0.f) ? r3 : (__expf(r3) - 1.f);
    }
    if (outF){
      float4 o = {r0, r1, r2, r3};
      *(float4*)(outF + (size_t)node*HC + 4*q) = o;
    }
    if (outB){
      union { bf16 h[4]; uint2 u; } cv;
      cv.h[0] = __float2bfloat16(r0); cv.h[1] = __float2bfloat16(r1);
      cv.h[2] = __float2bfloat16(r2); cv.h[3] = __float2bfloat16(r3);
      *(uint2*)(outB + (size_t)node*HC + 4*q) = cv.u;
    }
  }
}

// ---------------- fused mean-pool + relu + linear + sigmoid + BCE (wave per graph) ---
__global__ void __launch_bounds__(256) pool_logits_k(
    const float* __restrict__ h3, const int* __restrict__ goff,
    const float* __restrict__ Wl, const float* __restrict__ bl,
    const float* __restrict__ y, float* __restrict__ outp,
    float* __restrict__ lossAcc, int G)
{
  int lane = threadIdx.x & 63;
  int g = (blockIdx.x*256 + threadIdx.x) >> 6;
  if (g >= G) return;
  int n0 = goff[g], n1 = goff[g+1];
  int cnt = n1 - n0;
  float acc = 0.f, acc2 = 0.f, wl = 0.f;
  if (lane < 48){
    wl = Wl[lane];
    const float* p = h3 + (size_t)n0*48 + lane;
    int i = 0;
    for (; i + 2 <= cnt; i += 2){ acc += p[(size_t)i*48]; acc2 += p[(size_t)(i+1)*48]; }
    if (i < cnt) acc += p[(size_t)i*48];
    acc += acc2;
  }
  float inv = 1.f / fmaxf((float)cnt, 1.f);
  float v = fmaxf(acc*inv, 0.f) * wl;
  for (int o = 32; o > 0; o >>= 1) v += __shfl_down(v, o);
  if (lane == 0){
    float logit = v + bl[0];
    outp[g] = 1.f / (1.f + __expf(-logit));
    float t = y[g];
    float sp = (logit > 0.f) ? (logit + log1pf(__expf(-logit))) : log1pf(__expf(logit));
    atomicAdd(lossAcc, sp - t*logit);
  }
}

__global__ void fin_k(const float* __restrict__ lossAcc, float* __restrict__ outp, int gtot){
  outp[gtot] = lossAcc[0] / (float)gtot;
}

// ---------------- launch ----------------
extern "C" void kernel_launch(void* const* d_in, const int* in_sizes, int n_in,
                              void* d_out, int out_size, void* d_ws, size_t ws_size,
                              hipStream_t stream)
{
  (void)n_in; (void)out_size; (void)ws_size;
  const float* x    = (const float*)d_in[0];
  const float* y    = (const float*)d_in[1];
  const int*  ei    = (const int*)d_in[2];
  const int*  batch = (const int*)d_in[3];
  const float* W1 = (const float*)d_in[4];
  const float* as1= (const float*)d_in[5];
  const float* ad1= (const float*)d_in[6];
  const float* b1 = (const float*)d_in[7];
  const float* W2 = (const float*)d_in[8];
  const float* as2= (const float*)d_in[9];
  const float* ad2= (const float*)d_in[10];
  const float* b2 = (const float*)d_in[11];
  const float* W3 = (const float*)d_in[12];
  const float* as3= (const float*)d_in[13];
  const float* ad3= (const float*)d_in[14];
  const float* b3 = (const float*)d_in[15];
  const float* Wl = (const float*)d_in[16];
  const float* bl = (const float*)d_in[17];
  float* outp = (float*)d_out;

  int Nn = in_sizes[0] / 128;   // 100000 (multiple of 16)
  int Gg = in_sizes[1];
  int Ee = in_sizes[2] / 2;
  int ET = Ee + Nn;

  char* p = (char*)d_ws;
  auto carve = [&](size_t bytes) -> void* {
    void* r = (void*)p; p += (bytes + 255) & ~(size_t)255; return r;
  };
  int*   off     = (int*)  carve((size_t)(Nn+1)*4);
  int*   cnt     = (int*)  carve((size_t)Nn*4);
  int*   csr     = (int*)  carve((size_t)ET*4);
  int*   rank    = (int*)  carve((size_t)ET*4);
  int*   bsum    = (int*)  carve(256*4);
  float* aS4     = (float*)carve((size_t)Nn*4*4);
  float* aD4     = (float*)carve((size_t)Nn*4*4);
  int*   goff    = (int*)  carve((size_t)(Gg+1)*4);
  float* lossAcc = (float*)carve(4);
  bf16*  WT1     = (bf16*) carve((size_t)(192+16)*128*2);
  bf16*  WT2     = (bf16*) carve((size_t)(96+16)*192*2);
  bf16*  WT3     = (bf16*) carve((size_t)(48+16)*96*2);
  bf16*  bufH    = (bf16*) carve((size_t)Nn*192*2);   // GEMM out (h), agg in
  bf16*  bufA    = (bf16*) carve((size_t)Nn*192*2);   // GEMM A-operand
  // layer-3 f32 out for pooling: alias into the unused tail of bufH's region
  float* bufO    = (float*)((char*)bufH + ((size_t)Nn*96 + 255 & ~(size_t)255));

  int NB = (Nn + 1023) / 1024;
  int ebk = (ET + THREADS - 1) / THREADS;

  // CSR by destination (atomic-free scatter via rank)
  hipMemsetAsync(cnt, 0, (size_t)Nn*4, stream);
  hist_k<<<ebk, THREADS, 0, stream>>>(ei, cnt, rank, Ee, ET);
  scan1_k<<<NB, 1024, 0, stream>>>(cnt, off, bsum, Nn);
  scan2_k<<<1, 256, 0, stream>>>(bsum, NB);
  scan3_k<<<NB, 1024, 0, stream>>>(off, bsum, Nn);
  scatter_k<<<ebk, THREADS, 0, stream>>>(ei, off, rank, csr, Ee, ET);

  // dtype prep (x -> bf16) + consolidated weight prep + graph boundaries
  convf2b_k<<<(Nn*32 + THREADS-1)/THREADS, THREADS, 0, stream>>>((const float4*)x, (uint2*)bufA, Nn*32);
  int prepTot = 24576 + 18432 + 4608 + 768 + 1152 + 576 + (Gg + 1);
  prep_k<<<(prepTot + THREADS-1)/THREADS, THREADS, 0, stream>>>(
      W1, as1, ad1, W2, as2, ad2, W3, as3, ad3, WT1, WT2, WT3, batch, goff, Nn, Gg);

  int nRT = Nn / 16;                 // 6250 row tiles
  int gx  = (nRT + 3) / 4;           // 4 waves/block
  int gb1 = (Nn + 3) / 4;            // GRP=64: 1 node/wave
  int gb2 = (Nn + 7) / 8;            // GRP=32: 2 nodes/wave
  int gb3 = (Nn + 15) / 16;          // GRP=16: 4 nodes/wave

  // layer 1: 128 -> 3x64
  gemm_mfma_k<128,192><<<gx, 256, 0, stream>>>(bufA, WT1, bufH, aS4, aD4, nRT);
  agg_k<192,6,64><<<gb1, 256, 0, stream>>>(off, csr, bufH, aS4, aD4, b1, nullptr, bufA, Nn, 1);
  // layer 2: 192 -> 3x32
  gemm_mfma_k<192,96><<<gx, 256, 0, stream>>>(bufA, WT2, bufH, aS4, aD4, nRT);
  agg_k<96,5,32><<<gb2, 256, 0, stream>>>(off, csr, bufH, aS4, aD4, b2, nullptr, bufA, Nn, 1);
  // layer 3: 96 -> 3x16 (no ELU)
  gemm_mfma_k<96,48><<<gx, 256, 0, stream>>>(bufA, WT3, bufH, aS4, aD4, nRT);
  agg_k<48,4,16><<<gb3, 256, 0, stream>>>(off, csr, bufH, aS4, aD4, b3, bufO, nullptr, Nn, 0);

  // fused mean pool + relu + linear + sigmoid + BCE loss
  hipMemsetAsync(lossAcc, 0, 4, stream);
  pool_logits_k<<<(Gg + 3)/4, 256, 0, stream>>>(bufO, goff, Wl, bl, y, outp, lossAcc, Gg);
  fin_k<<<1, 1, 0, stream>>>(lossAcc, outp, Gg);
}

// Round 14
// 623.676 us; speedup vs baseline: 2.5727x; 1.0028x over previous
//
#include <hip/hip_runtime.h>
#include <hip/hip_bf16.h>

#define THREADS 256
typedef __hip_bfloat16 bf16;

typedef __bf16 v8bf __attribute__((ext_vector_type(8)));
typedef float  v4f  __attribute__((ext_vector_type(4)));

__device__ __forceinline__ float bfl(unsigned u){ return __uint_as_float(u << 16); }
__device__ __forceinline__ float bfh(unsigned u){ return __uint_as_float(u & 0xffff0000u); }

// ---------------- CSR build (group edges by destination) ----------------
__global__ void hist_k(const int* __restrict__ ei, int* __restrict__ cnt,
                       int* __restrict__ rank, int E, int ET){
  int i = blockIdx.x*THREADS + threadIdx.x;
  if (i >= ET) return;
  int d = (i < E) ? ei[E + i] : (i - E);   // self-loops appended
  rank[i] = atomicAdd(&cnt[d], 1);
}

__global__ void scan1_k(const int* __restrict__ deg, int* __restrict__ off,
                        int* __restrict__ bsum, int n){
  __shared__ int sh[1024];
  int i = blockIdx.x*1024 + threadIdx.x;
  int v = (i < n) ? deg[i] : 0;
  sh[threadIdx.x] = v;
  __syncthreads();
  for (int s = 1; s < 1024; s <<= 1){
    int t = (threadIdx.x >= s) ? sh[threadIdx.x - s] : 0;
    __syncthreads();
    sh[threadIdx.x] += t;
    __syncthreads();
  }
  if (i < n) off[i+1] = sh[threadIdx.x];
  if (threadIdx.x == 1023) bsum[blockIdx.x] = sh[1023];
}

__global__ void scan2_k(int* __restrict__ bsum, int nb){
  __shared__ int sh[256];
  int v = (threadIdx.x < nb) ? bsum[threadIdx.x] : 0;
  sh[threadIdx.x] = v;
  __syncthreads();
  for (int s = 1; s < 256; s <<= 1){
    int t = (threadIdx.x >= s) ? sh[threadIdx.x - s] : 0;
    __syncthreads();
    sh[threadIdx.x] += t;
    __syncthreads();
  }
  if (threadIdx.x < nb) bsum[threadIdx.x] = sh[threadIdx.x] - v;  // exclusive
}

__global__ void scan3_k(int* __restrict__ off, const int* __restrict__ bsum, int n){
  int i = blockIdx.x*1024 + threadIdx.x;
  if (i < n) off[i+1] += bsum[blockIdx.x];
  if (i == 0) off[0] = 0;
}

__global__ void scatter_k(const int* __restrict__ ei, const int* __restrict__ off,
                          const int* __restrict__ rank, int* __restrict__ csr,
                          int E, int ET){
  int i = blockIdx.x*THREADS + threadIdx.x;
  if (i >= ET) return;
  int s, d;
  if (i < E){ s = ei[i]; d = ei[E+i]; } else { s = i - E; d = i - E; }
  csr[off[d] + rank[i]] = s;
}

// ---------------- dtype prep ----------------
__global__ void convf2b_k(const float4* __restrict__ in, uint2* __restrict__ out, int n4){
  int i = blockIdx.x*THREADS + threadIdx.x;
  if (i >= n4) return;
  float4 v = in[i];
  union { bf16 h[4]; uint2 u; } cv;
  cv.h[0] = __float2bfloat16(v.x); cv.h[1] = __float2bfloat16(v.y);
  cv.h[2] = __float2bfloat16(v.z); cv.h[3] = __float2bfloat16(v.w);
  out[i] = cv.u;
}

__device__ __forceinline__ void wt_do(const float* __restrict__ W, bf16* __restrict__ WT,
                                      int K, int COUT, int i){
  int k = i / COUT, c = i - k*COUT;
  WT[(size_t)c*K + k] = __float2bfloat16(W[i]);
}

__device__ __forceinline__ void va_do(const float* __restrict__ W, const float* __restrict__ as,
                                      const float* __restrict__ ad, bf16* __restrict__ WTX,
                                      int K, int C, int COUT, int i){
  int k = i % K, c6 = i / K;
  int h = (c6 < 3) ? c6 : c6 - 3;
  const float* a = ((c6 < 3) ? as : ad) + h*C;
  const float* wp = W + (size_t)k*COUT + h*C;
  float s = 0.f;
  for (int cc = 0; cc < C; cc++) s += wp[cc]*a[cc];
  WTX[(size_t)(COUT + c6)*K + k] = __float2bfloat16(s);
}

// one launch: all W transposes + fused-alpha extra columns + graph boundaries
__global__ void prep_k(const float* __restrict__ W1, const float* __restrict__ as1, const float* __restrict__ ad1,
                       const float* __restrict__ W2, const float* __restrict__ as2, const float* __restrict__ ad2,
                       const float* __restrict__ W3, const float* __restrict__ as3, const float* __restrict__ ad3,
                       bf16* __restrict__ WT1, bf16* __restrict__ WT2, bf16* __restrict__ WT3,
                       const int* __restrict__ batch, int* __restrict__ goff, int n, int G)
{
  int i = blockIdx.x*THREADS + threadIdx.x;
  if (i < 24576){ wt_do(W1, WT1, 128, 192, i); return; } i -= 24576;
  if (i < 18432){ wt_do(W2, WT2, 192, 96, i); return; }  i -= 18432;
  if (i < 4608) { wt_do(W3, WT3, 96, 48, i); return; }   i -= 4608;
  if (i < 768)  { va_do(W1, as1, ad1, WT1, 128, 64, 192, i); return; } i -= 768;
  if (i < 1152) { va_do(W2, as2, ad2, WT2, 192, 32, 96, i); return; }  i -= 1152;
  if (i < 576)  { va_do(W3, as3, ad3, WT3, 96, 16, 48, i); return; }   i -= 576;
  if (i <= G){
    if (i == G){ goff[G] = n; return; }
    int lo = 0, hi = n;
    while (lo < hi){ int mid = (lo + hi) >> 1; if (batch[mid] < i) lo = mid + 1; else hi = mid; }
    goff[i] = lo;
  }
}

// ---------------- MFMA GEMM fused with alpha: C = A@B, aS/aD from extra tile ----
template<int K, int COUT>
__global__ void __launch_bounds__(256) gemm_mfma_k(
    const bf16* __restrict__ A, const bf16* __restrict__ BT,
    bf16* __restrict__ C, float* __restrict__ aS4, float* __restrict__ aD4,
    int nRowTiles)
{
  int wave = threadIdx.x >> 6, lane = threadIdx.x & 63;
  int rt = blockIdx.x*4 + wave;
  if (rt >= nRowTiles) return;
  int half = lane & 15;
  int quad = lane >> 4;
  const __bf16* aBase = (const __bf16*)A + (size_t)(rt*16 + half)*K + quad*8;
  v8bf aF[K/32];
  #pragma unroll
  for (int kk = 0; kk < K/32; kk++) aF[kk] = *(const v8bf*)(aBase + kk*32);
  #pragma unroll
  for (int cb = 0; cb < COUT + 16; cb += 16){
    const __bf16* bBase = (const __bf16*)BT + (size_t)(cb + half)*K + quad*8;
    v4f acc = {0.f, 0.f, 0.f, 0.f};
    #pragma unroll
    for (int kk = 0; kk < K/32; kk++)
      acc = __builtin_amdgcn_mfma_f32_16x16x32_bf16(aF[kk], *(const v8bf*)(bBase + kk*32), acc, 0, 0, 0);
    int orow = rt*16 + quad*4;                 // D: col=lane&15, row=quad*4+reg
    if (cb < COUT){
      bf16* cp = C + (size_t)orow*COUT + cb + half;
      #pragma unroll
      for (int r = 0; r < 4; r++)
        cp[(size_t)r*COUT] = __float2bfloat16(acc[r]);
    } else if (half < 6){
      #pragma unroll
      for (int r = 0; r < 4; r++){
        int row = orow + r;
        if (half < 3) aS4[row*4 + half]     = acc[r];
        else          aD4[row*4 + half - 3] = acc[r];
      }
    }
  }
}

// ---------------- fused softmax-weight + aggregation (GRP lanes per dst node) -------
// Phase A: lane q computes edge (base+q)'s 3 exp-weights, stores {w_h, src} per head.
// Phase B: active lanes stream their OWN head's array via broadcast ds_read_b128
// (2 edges per read), 8 independent h-gathers in flight (explicit scalars).
template<int HC, int CSH, int GRP>
__global__ void __launch_bounds__(256) agg_k(
    const int* __restrict__ off, const int* __restrict__ csr,
    const bf16* __restrict__ hbuf,
    const float* __restrict__ aS4, const float* __restrict__ aD4,
    const float* __restrict__ bias,
    float* __restrict__ outF, bf16* __restrict__ outB,
    int n, int doElu)
{
  constexpr int NPW = 64 / GRP;
  __shared__ __align__(16) float wls[4][384];   // per wave: NPW groups x 3 heads x GRP float2
  int tid = threadIdx.x;
  int wave = tid >> 6;
  int lane = tid & 63;
  int q = lane % GRP;
  int grp = lane / GRP;
  int wv = (blockIdx.x*256 + tid) >> 6;
  int node = wv*NPW + grp;
  bool valid = node < n;
  int e0 = 0, e1 = 0;
  float4 ad = {0.f, 0.f, 0.f, 0.f};
  if (valid){
    e0 = off[node]; e1 = off[node+1];
    ad = *(const float4*)(aD4 + 4*node);
  }
  const int hq = (4*q) >> CSH;               // head of this lane's 4 channels
  const bool act = valid && (q < HC/4);
  const size_t hoff = 4*q;
  float dh = 0.f;
  float a0 = 0.f, a1 = 0.f, a2 = 0.f, a3 = 0.f;
  float* gbase = &wls[wave][grp*3*GRP*2];    // this group's region
  const float* wh = gbase + hq*GRP*2;        // own-head stream (phase B)

  int nch = (e1 - e0 + GRP - 1) / GRP;
  for (int c = 0; c < nch; c++){
    int base = e0 + c*GRP;
    __threadfence_block();                   // WAR: prior chunk's reads drained
    int j = base + q;
    if (j < e1){
      int s = csr[j];
      float4 av = *(const float4*)(aS4 + 4*s);
      float x0 = av.x + ad.x; x0 = (x0 > 0.f) ? x0 : 0.2f*x0;
      float x1 = av.y + ad.y; x1 = (x1 > 0.f) ? x1 : 0.2f*x1;
      float x2 = av.z + ad.z; x2 = (x2 > 0.f) ? x2 : 0.2f*x2;
      float sf = __int_as_float(s);
      float2 p0 = {__expf(x0), sf};
      float2 p1 = {__expf(x1), sf};
      float2 p2 = {__expf(x2), sf};
      *(float2*)(gbase + (0*GRP + q)*2) = p0;
      *(float2*)(gbase + (1*GRP + q)*2) = p1;
      *(float2*)(gbase + (2*GRP + q)*2) = p2;
    }
    __threadfence_block();                   // writes visible within wave
    if (act){
      int lim = e1 - base; if (lim > GRP) lim = GRP;
      int jj = 0;
      for (; jj + 8 <= lim; jj += 8){
        float4 pA = *(const float4*)(wh + jj*2);        // edges jj, jj+1
        float4 pB = *(const float4*)(wh + jj*2 + 4);    // edges jj+2, jj+3
        float4 pC = *(const float4*)(wh + jj*2 + 8);    // edges jj+4, jj+5
        float4 pD = *(const float4*)(wh + jj*2 + 12);   // edges jj+6, jj+7
        int s0 = __float_as_int(pA.y), s1 = __float_as_int(pA.w);
        int s2 = __float_as_int(pB.y), s3 = __float_as_int(pB.w);
        int s4 = __float_as_int(pC.y), s5 = __float_as_int(pC.w);
        int s6 = __float_as_int(pD.y), s7 = __float_as_int(pD.w);
        float w0 = pA.x, w1 = pA.z, w2 = pB.x, w3 = pB.z;
        float w4 = pC.x, w5 = pC.z, w6 = pD.x, w7 = pD.z;
        uint2 u0 = *(const uint2*)(hbuf + (size_t)s0*HC + hoff);
        uint2 u1 = *(const uint2*)(hbuf + (size_t)s1*HC + hoff);
        uint2 u2 = *(const uint2*)(hbuf + (size_t)s2*HC + hoff);
        uint2 u3 = *(const uint2*)(hbuf + (size_t)s3*HC + hoff);
        uint2 u4 = *(const uint2*)(hbuf + (size_t)s4*HC + hoff);
        uint2 u5 = *(const uint2*)(hbuf + (size_t)s5*HC + hoff);
        uint2 u6 = *(const uint2*)(hbuf + (size_t)s6*HC + hoff);
        uint2 u7 = *(const uint2*)(hbuf + (size_t)s7*HC + hoff);
        dh += w0 + w1 + w2 + w3 + w4 + w5 + w6 + w7;
        a0 += w0*bfl(u0.x); a1 += w0*bfh(u0.x); a2 += w0*bfl(u0.y); a3 += w0*bfh(u0.y);
        a0 += w1*bfl(u1.x); a1 += w1*bfh(u1.x); a2 += w1*bfl(u1.y); a3 += w1*bfh(u1.y);
        a0 += w2*bfl(u2.x); a1 += w2*bfh(u2.x); a2 += w2*bfl(u2.y); a3 += w2*bfh(u2.y);
        a0 += w3*bfl(u3.x); a1 += w3*bfh(u3.x); a2 += w3*bfl(u3.y); a3 += w3*bfh(u3.y);
        a0 += w4*bfl(u4.x); a1 += w4*bfh(u4.x); a2 += w4*bfl(u4.y); a3 += w4*bfh(u4.y);
        a0 += w5*bfl(u5.x); a1 += w5*bfh(u5.x); a2 += w5*bfl(u5.y); a3 += w5*bfh(u5.y);
        a0 += w6*bfl(u6.x); a1 += w6*bfh(u6.x); a2 += w6*bfl(u6.y); a3 += w6*bfh(u6.y);
        a0 += w7*bfl(u7.x); a1 += w7*bfh(u7.x); a2 += w7*bfl(u7.y); a3 += w7*bfh(u7.y);
      }
      for (; jj + 4 <= lim; jj += 4){
        float4 pA = *(const float4*)(wh + jj*2);
        float4 pB = *(const float4*)(wh + jj*2 + 4);
        int s0 = __float_as_int(pA.y), s1 = __float_as_int(pA.w);
        int s2 = __float_as_int(pB.y), s3 = __float_as_int(pB.w);
        float w0 = pA.x, w1 = pA.z, w2 = pB.x, w3 = pB.z;
        uint2 u0 = *(const uint2*)(hbuf + (size_t)s0*HC + hoff);
        uint2 u1 = *(const uint2*)(hbuf + (size_t)s1*HC + hoff);
        uint2 u2 = *(const uint2*)(hbuf + (size_t)s2*HC + hoff);
        uint2 u3 = *(const uint2*)(hbuf + (size_t)s3*HC + hoff);
        dh += w0 + w1 + w2 + w3;
        a0 += w0*bfl(u0.x); a1 += w0*bfh(u0.x); a2 += w0*bfl(u0.y); a3 += w0*bfh(u0.y);
        a0 += w1*bfl(u1.x); a1 += w1*bfh(u1.x); a2 += w1*bfl(u1.y); a3 += w1*bfh(u1.y);
        a0 += w2*bfl(u2.x); a1 += w2*bfh(u2.x); a2 += w2*bfl(u2.y); a3 += w2*bfh(u2.y);
        a0 += w3*bfl(u3.x); a1 += w3*bfh(u3.x); a2 += w3*bfl(u3.y); a3 += w3*bfh(u3.y);
      }
      for (; jj < lim; jj++){
        float2 pw = *(const float2*)(wh + jj*2);
        int s = __float_as_int(pw.y);
        float w = pw.x;
        uint2 u = *(const uint2*)(hbuf + (size_t)s*HC + hoff);
        dh += w;
        a0 += w*bfl(u.x); a1 += w*bfh(u.x); a2 += w*bfl(u.y); a3 += w*bfh(u.y);
      }
    }
  }
  if (act){
    float inv = 1.f / (dh + 1e-16f);
    const float4 b = *(const float4*)(bias + 4*q);
    float r0 = a0*inv + b.x, r1 = a1*inv + b.y, r2 = a2*inv + b.z, r3 = a3*inv + b.w;
    if (doElu){
      r0 = (r0 > 0.f) ? r0 : (__expf(r0) - 1.f);
      r1 = (r1 > 0.f) ? r1 : (__expf(r1) - 1.f);
      r2 = (r2 > 0.f) ? r2 : (__expf(r2) - 1.f);
      r3 = (r3 > 0.f) ? r3 : (__expf(r3) - 1.f);
    }
    if (outF){
      float4 o = {r0, r1, r2, r3};
      *(float4*)(outF + (size_t)node*HC + 4*q) = o;
    }
    if (outB){
      union { bf16 h[4]; uint2 u; } cv;
      cv.h[0] = __float2bfloat16(r0); cv.h[1] = __float2bfloat16(r1);
      cv.h[2] = __float2bfloat16(r2); cv.h[3] = __float2bfloat16(r3);
      *(uint2*)(outB + (size_t)node*HC + 4*q) = cv.u;
    }
  }
}

// ---------------- fused mean-pool + relu + linear + sigmoid + BCE (wave per graph) ---
__global__ void __launch_bounds__(256) pool_logits_k(
    const float* __restrict__ h3, const int* __restrict__ goff,
    const float* __restrict__ Wl, const float* __restrict__ bl,
    const float* __restrict__ y, float* __restrict__ outp,
    float* __restrict__ lossAcc, int G)
{
  int lane = threadIdx.x & 63;
  int g = (blockIdx.x*256 + threadIdx.x) >> 6;
  if (g >= G) return;
  int n0 = goff[g], n1 = goff[g+1];
  int cnt = n1 - n0;
  float acc = 0.f, acc2 = 0.f, wl = 0.f;
  if (lane < 48){
    wl = Wl[lane];
    const float* p = h3 + (size_t)n0*48 + lane;
    int i = 0;
    for (; i + 2 <= cnt; i += 2){ acc += p[(size_t)i*48]; acc2 += p[(size_t)(i+1)*48]; }
    if (i < cnt) acc += p[(size_t)i*48];
    acc += acc2;
  }
  float inv = 1.f / fmaxf((float)cnt, 1.f);
  float v = fmaxf(acc*inv, 0.f) * wl;
  for (int o = 32; o > 0; o >>= 1) v += __shfl_down(v, o);
  if (lane == 0){
    float logit = v + bl[0];
    outp[g] = 1.f / (1.f + __expf(-logit));
    float t = y[g];
    float sp = (logit > 0.f) ? (logit + log1pf(__expf(-logit))) : log1pf(__expf(logit));
    atomicAdd(lossAcc, sp - t*logit);
  }
}

__global__ void fin_k(const float* __restrict__ lossAcc, float* __restrict__ outp, int gtot){
  outp[gtot] = lossAcc[0] / (float)gtot;
}

// ---------------- launch ----------------
extern "C" void kernel_launch(void* const* d_in, const int* in_sizes, int n_in,
                              void* d_out, int out_size, void* d_ws, size_t ws_size,
                              hipStream_t stream)
{
  (void)n_in; (void)out_size; (void)ws_size;
  const float* x    = (const float*)d_in[0];
  const float* y    = (const float*)d_in[1];
  const int*  ei    = (const int*)d_in[2];
  const int*  batch = (const int*)d_in[3];
  const float* W1 = (const float*)d_in[4];
  const float* as1= (const float*)d_in[5];
  const float* ad1= (const float*)d_in[6];
  const float* b1 = (const float*)d_in[7];
  const float* W2 = (const float*)d_in[8];
  const float* as2= (const float*)d_in[9];
  const float* ad2= (const float*)d_in[10];
  const float* b2 = (const float*)d_in[11];
  const float* W3 = (const float*)d_in[12];
  const float* as3= (const float*)d_in[13];
  const float* ad3= (const float*)d_in[14];
  const float* b3 = (const float*)d_in[15];
  const float* Wl = (const float*)d_in[16];
  const float* bl = (const float*)d_in[17];
  float* outp = (float*)d_out;

  int Nn = in_sizes[0] / 128;   // 100000 (multiple of 16)
  int Gg = in_sizes[1];
  int Ee = in_sizes[2] / 2;
  int ET = Ee + Nn;

  char* p = (char*)d_ws;
  auto carve = [&](size_t bytes) -> void* {
    void* r = (void*)p; p += (bytes + 255) & ~(size_t)255; return r;
  };
  int*   off     = (int*)  carve((size_t)(Nn+1)*4);
  int*   cnt     = (int*)  carve((size_t)Nn*4);
  int*   csr     = (int*)  carve((size_t)ET*4);
  int*   rank    = (int*)  carve((size_t)ET*4);
  int*   bsum    = (int*)  carve(256*4);
  float* aS4     = (float*)carve((size_t)Nn*4*4);
  float* aD4     = (float*)carve((size_t)Nn*4*4);
  int*   goff    = (int*)  carve((size_t)(Gg+1)*4);
  float* lossAcc = (float*)carve(4);
  bf16*  WT1     = (bf16*) carve((size_t)(192+16)*128*2);
  bf16*  WT2     = (bf16*) carve((size_t)(96+16)*192*2);
  bf16*  WT3     = (bf16*) carve((size_t)(48+16)*96*2);
  bf16*  bufH    = (bf16*) carve((size_t)Nn*192*2);   // GEMM out (h), agg in
  bf16*  bufA    = (bf16*) carve((size_t)Nn*192*2);   // GEMM A-operand
  // layer-3 f32 out for pooling: alias into the unused tail of bufH's region
  float* bufO    = (float*)((char*)bufH + ((size_t)Nn*96 + 255 & ~(size_t)255));

  int NB = (Nn + 1023) / 1024;
  int ebk = (ET + THREADS - 1) / THREADS;

  // CSR by destination (atomic-free scatter via rank)
  hipMemsetAsync(cnt, 0, (size_t)Nn*4, stream);
  hist_k<<<ebk, THREADS, 0, stream>>>(ei, cnt, rank, Ee, ET);
  scan1_k<<<NB, 1024, 0, stream>>>(cnt, off, bsum, Nn);
  scan2_k<<<1, 256, 0, stream>>>(bsum, NB);
  scan3_k<<<NB, 1024, 0, stream>>>(off, bsum, Nn);
  scatter_k<<<ebk, THREADS, 0, stream>>>(ei, off, rank, csr, Ee, ET);

  // dtype prep (x -> bf16) + consolidated weight prep + graph boundaries
  convf2b_k<<<(Nn*32 + THREADS-1)/THREADS, THREADS, 0, stream>>>((const float4*)x, (uint2*)bufA, Nn*32);
  int prepTot = 24576 + 18432 + 4608 + 768 + 1152 + 576 + (Gg + 1);
  prep_k<<<(prepTot + THREADS-1)/THREADS, THREADS, 0, stream>>>(
      W1, as1, ad1, W2, as2, ad2, W3, as3, ad3, WT1, WT2, WT3, batch, goff, Nn, Gg);

  int nRT = Nn / 16;                 // 6250 row tiles
  int gx  = (nRT + 3) / 4;           // 4 waves/block
  int gb1 = (Nn + 3) / 4;            // GRP=64: 1 node/wave
  int gb2 = (Nn + 7) / 8;            // GRP=32: 2 nodes/wave
  int gb3 = (Nn + 15) / 16;          // GRP=16: 4 nodes/wave

  // layer 1: 128 -> 3x64
  gemm_mfma_k<128,192><<<gx, 256, 0, stream>>>(bufA, WT1, bufH, aS4, aD4, nRT);
  agg_k<192,6,64><<<gb1, 256, 0, stream>>>(off, csr, bufH, aS4, aD4, b1, nullptr, bufA, Nn, 1);
  // layer 2: 192 -> 3x32
  gemm_mfma_k<192,96><<<gx, 256, 0, stream>>>(bufA, WT2, bufH, aS4, aD4, nRT);
  agg_k<96,5,32><<<gb2, 256, 0, stream>>>(off, csr, bufH, aS4, aD4, b2, nullptr, bufA, Nn, 1);
  // layer 3: 96 -> 3x16 (no ELU)
  gemm_mfma_k<96,48><<<gx, 256, 0, stream>>>(bufA, WT3, bufH, aS4, aD4, nRT);
  agg_k<48,4,16><<<gb3, 256, 0, stream>>>(off, csr, bufH, aS4, aD4, b3, bufO, nullptr, Nn, 0);

  // fused mean pool + relu + linear + sigmoid + BCE loss
  hipMemsetAsync(lossAcc, 0, 4, stream);
  pool_logits_k<<<(Gg + 3)/4, 256, 0, stream>>>(bufO, goff, Wl, bl, y, outp, lossAcc, Gg);
  fin_k<<<1, 1, 0, stream>>>(lossAcc, outp, Gg);
}